// Round 6
// baseline (321.799 us; speedup 1.0000x reference)
//
#include <hip/hip_runtime.h>
#include <hip/hip_bf16.h>
#include <stdint.h>

#define MM 16384
#define DD 256
#define HH 4
#define KK 16
#define DFF_ 1024

typedef __attribute__((ext_vector_type(8))) short bf16x8;
typedef __attribute__((ext_vector_type(16))) float f32x16;
typedef __attribute__((ext_vector_type(2))) float f32x2;

__device__ __forceinline__ unsigned short f2bf(float f) {
    unsigned u = __builtin_bit_cast(unsigned, f);
    unsigned r = u + 0x7fffu + ((u >> 16) & 1u);
    return (unsigned short)(r >> 16);
}
__device__ __forceinline__ float bf2f(unsigned short h) {
    unsigned u = ((unsigned)h) << 16;
    return __builtin_bit_cast(float, u);
}

// ---------------------------------------------------------------------------
// Fragment layouts (bf16, 16B chunks of 8 elems):
// A-frag (row m, k):  chunk = ((m>>5)*(KD/16) + (k>>4))*64 + ((k>>3)&1)*32 + (m&31), elem = k&7
// B-frag (col n, k):  same with n.
// v_mfma_f32_32x32x16_bf16 C/D: col=lane&31, row=(reg&3)+8*(reg>>2)+4*(lane>>5)
// kv buffer: fp8 e4m3 rows of 512 B, groups of 8 B = [K4 | V4].
// NOTE (R5): gelu: sigmoid form + pad-33 LDS + no barriers.
// NOTE (R9/R11/R12): ALL LDS-staging variants lose to direct frag loads.
//   R12 halved VMEM+L2 demand and still lost -> GEMMs are NOT L2-BW bound.
// NOTE (R10): gemm_ln fusion (Wo+LN2, FFN2+LN1') + ln3 merge: 349->335.7us.
// NOTE (R14): GRID STARVATION is the real lever: gemm_ln 1->2 waves/SIMD and
//   final FFN2 2x grid: 335.7->311.8us, prediction matched.
// NOTE (R15/this round): push TLP further on the under-fed dispatches:
//   gemm_ln -> 16 waves of 32x32 (4/SIMD, acc 16 regs, 1A+1B per MFMA);
//   gemm_qkv -> 8 waves of 64x32 (6/SIMD); final FFN2 -> 8 waves of 32x32
//   (4/SIMD). FFN1 (4/SIMD) and attn (16/SIMD) unchanged.
// ---------------------------------------------------------------------------

// wfrag layout (shorts): WQF@0 (blk stride 65536), KVF@131072 (131072),
//   WOF@393216 (65536), W1F@524288 (262144), W2F@1048576 (262144)
__global__ __launch_bounds__(256) void prep_weights(
        const float* __restrict__ Wq, const float* __restrict__ Wk,
        const float* __restrict__ Wv, const float* __restrict__ Wo,
        const float* __restrict__ W1, const float* __restrict__ W2,
        unsigned short* __restrict__ wf) {
    int t = blockIdx.x * blockDim.x + threadIdx.x;
    const float* src; unsigned short* dst;
    int kd, lg, rem, blk, e, sect;
    if (t < 131072) { sect = 0; rem = t; blk = rem >> 16; e = rem & 65535;
        src = Wq; dst = wf + blk * 65536; kd = 256; lg = 8; }
    else if (t < 262144) { sect = 1; rem = t - 131072; blk = rem >> 16; e = rem & 65535;
        src = Wk; dst = wf + 131072 + blk * 131072; kd = 256; lg = 8; }
    else if (t < 393216) { sect = 2; rem = t - 262144; blk = rem >> 16; e = rem & 65535;
        src = Wv; dst = wf + 131072 + blk * 131072; kd = 256; lg = 8; }
    else if (t < 524288) { sect = 0; rem = t - 393216; blk = rem >> 16; e = rem & 65535;
        src = Wo; dst = wf + 393216 + blk * 65536; kd = 256; lg = 8; }
    else if (t < 1048576) { sect = 0; rem = t - 524288; blk = rem >> 18; e = rem & 262143;
        src = W1; dst = wf + 524288 + blk * 262144; kd = 256; lg = 10; }
    else if (t < 1572864) { sect = 0; rem = t - 1048576; blk = rem >> 18; e = rem & 262143;
        src = W2; dst = wf + 1048576 + blk * 262144; kd = 1024; lg = 8; }
    else return;
    int k = e >> lg;
    int n = e & ((1 << lg) - 1);
    if (sect == 1) n = (n >> 2) * 8 + (n & 3);
    else if (sect == 2) n = (n >> 2) * 8 + 4 + (n & 3);
    float v = src[(size_t)blk * kd * (1 << lg) + e];
    int off = ((n >> 5) * (kd >> 4) + (k >> 4)) * 512 + (((k >> 3) & 1) * 32 + (n & 31)) * 8 + (k & 7);
    dst[off] = f2bf(v);
}

// 3 slices in one launch: y=0: LN(xa,g,b)->outln; y=1: conv(xa)->outca; y=2: conv(xb)->outcb
__global__ __launch_bounds__(256) void ln3_to_frag(
        const float* __restrict__ xa, const float* __restrict__ g,
        const float* __restrict__ b, const float* __restrict__ xb,
        unsigned short* __restrict__ outln, unsigned short* __restrict__ outca,
        unsigned short* __restrict__ outcb) {
    int y = blockIdx.y;
    const float* x = (y == 2) ? xb : xa;
    unsigned short* out = (y == 0) ? outln : (y == 1 ? outca : outcb);
    int apply_ln = (y == 0);
    int wave = threadIdx.x >> 6, lane = threadIdx.x & 63;
    int m = blockIdx.x * 4 + wave;
    const float4 xv = reinterpret_cast<const float4*>(x + (size_t)m * DD)[lane];
    float vals[4] = {xv.x, xv.y, xv.z, xv.w};
    int k0 = lane * 4;
    if (apply_ln) {
        float s = vals[0] + vals[1] + vals[2] + vals[3];
        float sq = vals[0]*vals[0] + vals[1]*vals[1] + vals[2]*vals[2] + vals[3]*vals[3];
        for (int o = 32; o; o >>= 1) { s += __shfl_xor(s, o, 64); sq += __shfl_xor(sq, o, 64); }
        float mean = s * (1.0f / DD);
        float var = sq * (1.0f / DD) - mean * mean;
        float rs = rsqrtf(var + 1e-5f);
        #pragma unroll
        for (int c = 0; c < 4; ++c)
            vals[c] = (vals[c] - mean) * rs * g[k0 + c] + b[k0 + c];
    }
    int chunk = ((m >> 5) * (DD >> 4) + (k0 >> 4)) * 64 + ((k0 >> 3) & 1) * 32 + (m & 31);
    ushort4 o4 = make_ushort4(f2bf(vals[0]), f2bf(vals[1]), f2bf(vals[2]), f2bf(vals[3]));
    *reinterpret_cast<ushort4*>(out + (size_t)chunk * 8 + (k0 & 7)) = o4;
}

constexpr int GOUT_F32 = 0;
constexpr int GOUT_GELU_FRAG = 2;

template <int KG>
__device__ __forceinline__ void compute_tile(
        const bf16x8* __restrict__ a0, const bf16x8* __restrict__ a1,
        const bf16x8* __restrict__ b0, const bf16x8* __restrict__ b1,
        f32x16 acc[2][2]) {
    #pragma unroll 4
    for (int g = 0; g < KG; ++g) {
        bf16x8 av0 = a0[g * 64];
        bf16x8 av1 = a1[g * 64];
        bf16x8 bv0 = b0[g * 64];
        bf16x8 bv1 = b1[g * 64];
        acc[0][0] = __builtin_amdgcn_mfma_f32_32x32x16_bf16(av0, bv0, acc[0][0], 0, 0, 0);
        acc[0][1] = __builtin_amdgcn_mfma_f32_32x32x16_bf16(av0, bv1, acc[0][1], 0, 0, 0);
        acc[1][0] = __builtin_amdgcn_mfma_f32_32x32x16_bf16(av1, bv0, acc[1][0], 0, 0, 0);
        acc[1][1] = __builtin_amdgcn_mfma_f32_32x32x16_bf16(av1, bv1, acc[1][1], 0, 0, 0);
    }
}

// C = A(frag) x B(frag). wg = 128x128 tile, 4 waves = 2m x 2n, each 64x64,
// serial K, direct frag loads (proven R10 structure). Used for FFN1/GELU.
template <int KD, int NOUT, int MODE, bool RESID, bool BIAS>
__global__ __launch_bounds__(256) void gemm_frag(
        const bf16x8* __restrict__ A, const bf16x8* __restrict__ B,
        void* __restrict__ outp, const float* __restrict__ resid,
        const float* __restrict__ bias, int out_kd) {
    constexpr int KG = KD / 16;
    __shared__ float lds[MODE == GOUT_GELU_FRAG ? 4 * 1056 : 4];
    int wave = threadIdx.x >> 6, lane = threadIdx.x & 63;
    int wm = wave & 1, wn = wave >> 1;
    int m0 = blockIdx.x * 128 + wm * 64;
    int n0 = blockIdx.y * 128 + wn * 64;
    const bf16x8* a0 = A + ((size_t)(m0 >> 5) * KG) * 64 + lane;
    const bf16x8* a1 = a0 + (size_t)KG * 64;
    const bf16x8* b0 = B + ((size_t)(n0 >> 5) * KG) * 64 + lane;
    const bf16x8* b1 = b0 + (size_t)KG * 64;
    f32x16 acc[2][2] = {};
    compute_tile<KG>(a0, a1, b0, b1, acc);
    int col = lane & 31, rq = (lane >> 5) * 4;
    if constexpr (MODE == GOUT_F32) {
        #pragma unroll
        for (int i = 0; i < 2; ++i)
        #pragma unroll
        for (int j = 0; j < 2; ++j) {
            #pragma unroll
            for (int r = 0; r < 16; ++r) {
                int row = (r & 3) + 8 * (r >> 2) + rq;
                int m = m0 + i * 32 + row;
                int n = n0 + j * 32 + col;
                float v = acc[i][j][r];
                if (BIAS) v += bias[n];
                if (RESID) v += resid[(size_t)m * NOUT + n];
                ((float*)outp)[(size_t)m * NOUT + n] = v;
            }
        }
    } else {
        // GELU -> bf16 A-frag. Wave-private pad-33 tile, no barriers.
        float* wlds = &lds[wave * 1056];
        for (int i = 0; i < 2; ++i)
        for (int j = 0; j < 2; ++j) {
            #pragma unroll
            for (int r = 0; r < 16; ++r) {
                int row = (r & 3) + 8 * (r >> 2) + rq;
                int n = n0 + j * 32 + col;
                float v = acc[i][j][r] + bias[n];
                float arg = v * (1.5957691216f + 0.0713548163f * v * v);
                v = v * __frcp_rn(1.0f + __expf(-arg));
                wlds[row * 33 + col] = v;
            }
            #pragma unroll
            for (int it = 0; it < 2; ++it) {
                int task = lane + it * 64;
                int row = task >> 2, cc = task & 3;
                int m = m0 + i * 32 + row;
                int k = n0 + j * 32 + cc * 8;
                float* p = &wlds[row * 33 + cc * 8];
                unsigned short us[8];
                #pragma unroll
                for (int e = 0; e < 8; ++e) us[e] = f2bf(p[e]);
                int chunk = ((m >> 5) * (out_kd >> 4) + (k >> 4)) * 64 + ((k >> 3) & 1) * 32 + (m & 31);
                reinterpret_cast<uint4*>(outp)[chunk] = *reinterpret_cast<uint4*>(us);
            }
        }
    }
}

// R15: final FFN2. wg = 64x128 tile, 512 thr / 8 waves = 2m x 4n of 32x32.
// grid (M/64, N/128) -> 512 wgs x 8 waves = 4 waves/SIMD.
template <int KD, int NOUT, bool RESID, bool BIAS>
__global__ __launch_bounds__(512) void gemm_frag64(
        const bf16x8* __restrict__ A, const bf16x8* __restrict__ B,
        float* __restrict__ outp, const float* __restrict__ resid,
        const float* __restrict__ bias) {
    constexpr int KG = KD / 16;
    int wave = threadIdx.x >> 6, lane = threadIdx.x & 63;
    int wm = wave & 1, wn = wave >> 1;
    int mw = blockIdx.x * 64 + wm * 32;
    int nw = blockIdx.y * 128 + wn * 32;
    const bf16x8* a0 = A + ((size_t)(mw >> 5) * KG) * 64 + lane;
    const bf16x8* b0 = B + ((size_t)(nw >> 5) * KG) * 64 + lane;
    f32x16 acc = {};
    #pragma unroll 8
    for (int g = 0; g < KG; ++g)
        acc = __builtin_amdgcn_mfma_f32_32x32x16_bf16(a0[g * 64], b0[g * 64], acc, 0, 0, 0);
    int col = lane & 31, rq = (lane >> 5) * 4;
    #pragma unroll
    for (int r = 0; r < 16; ++r) {
        int row = (r & 3) + 8 * (r >> 2) + rq;
        int m = mw + row;
        int n = nw + col;
        float v = acc[r];
        if (BIAS) v += bias[n];
        if (RESID) v += resid[(size_t)m * NOUT + n];
        outp[(size_t)m * NOUT + n] = v;
    }
}

// R15: fused Q + KV projections. 512 thr / 8 waves = 2m x 4n of 64x32.
// grid (M/128, 6) -> 768 wgs x 8 waves = 6 waves/SIMD.
__global__ __launch_bounds__(512) void gemm_qkv(
        const bf16x8* __restrict__ Aq, const bf16x8* __restrict__ Akv,
        const bf16x8* __restrict__ Bq, const bf16x8* __restrict__ Bkv,
        unsigned short* __restrict__ qout, unsigned char* __restrict__ kvout) {
    constexpr int KG = 16;
    int wave = threadIdx.x >> 6, lane = threadIdx.x & 63;
    int wm = wave & 1, wn = wave >> 1;   // wm 0..1 (64-row half), wn 0..3 (32-col)
    int y = blockIdx.y;
    bool isQ = y < 2;
    const bf16x8* A = isQ ? Aq : Akv;
    const bf16x8* B = isQ ? Bq : Bkv;
    int m0 = blockIdx.x * 128 + wm * 64;
    int n0 = (isQ ? y : y - 2) * 128 + wn * 32;
    const bf16x8* a0 = A + ((size_t)(m0 >> 5) * KG) * 64 + lane;
    const bf16x8* a1 = a0 + (size_t)KG * 64;
    const bf16x8* b0 = B + ((size_t)(n0 >> 5) * KG) * 64 + lane;
    f32x16 acc[2] = {};
    #pragma unroll 4
    for (int g = 0; g < KG; ++g) {
        bf16x8 av0 = a0[g * 64];
        bf16x8 av1 = a1[g * 64];
        bf16x8 bv = b0[g * 64];
        acc[0] = __builtin_amdgcn_mfma_f32_32x32x16_bf16(av0, bv, acc[0], 0, 0, 0);
        acc[1] = __builtin_amdgcn_mfma_f32_32x32x16_bf16(av1, bv, acc[1], 0, 0, 0);
    }
    int col = lane & 31, rq = (lane >> 5) * 4;
    #pragma unroll
    for (int i = 0; i < 2; ++i)
    #pragma unroll
    for (int r = 0; r < 16; ++r) {
        int row = (r & 3) + 8 * (r >> 2) + rq;
        int m = m0 + i * 32 + row;
        int n = n0 + col;
        float v = acc[i][r];
        if (isQ) qout[(size_t)m * 256 + n] = f2bf(v);
        else kvout[(size_t)m * 512 + n] =
            (unsigned char)(__builtin_amdgcn_cvt_pk_fp8_f32(v, v, 0, false) & 0xff);
    }
}

// butterfly reduce-scatter stage: N slots -> N/2 slots (xor-butterfly).
template <int O, int N>
__device__ __forceinline__ void redstage(float* a, int lane) {
    int sel = lane & O;
    #pragma unroll
    for (int u = 0; u < N / 2; ++u) {
        float lo = a[2 * u], hi = a[2 * u + 1];
        float keep = sel ? hi : lo;
        float send = sel ? lo : hi;
        a[u] = keep + __shfl_xor(send, O, 64);
    }
}

// Fused: C = A(frag) x B(frag) [+bias] + resid ; write f32 C; then
// LayerNorm rows of C -> bf16 A-frag output.
// R15: wg = 64 rows x 256 cols with 16 WAVES (1024 thr), 2m x 8n of 32x32
// -> 4 waves/SIMD, acc 16 regs, 1A+1B load per MFMA.
template <int KD, bool BIAS>
__global__ __launch_bounds__(1024) void gemm_ln(
        const bf16x8* __restrict__ A, const bf16x8* __restrict__ B,
        float* __restrict__ out_f32, const float* __restrict__ resid,
        const float* __restrict__ bias,
        const float* __restrict__ lng, const float* __restrict__ lnb,
        unsigned short* __restrict__ out_frag) {
    constexpr int KG = KD / 16;
    __shared__ float pstat[8][64][2];   // [wn][block row][sum,sumsq]
    __shared__ float stats[64][2];      // [block row][mean, rstd]
    __shared__ float tlds[16][32 * 33]; // per-wave transpose pads
    int wave = threadIdx.x >> 6, lane = threadIdx.x & 63;
    int wm = wave >> 3, wn = wave & 7;
    int m0 = blockIdx.x * 64;
    int mw = m0 + wm * 32;
    int n0 = wn * 32;
    const bf16x8* a0 = A + ((size_t)(mw >> 5) * KG) * 64 + lane;
    const bf16x8* b0 = B + ((size_t)(n0 >> 5) * KG) * 64 + lane;
    f32x16 acc = {};
    #pragma unroll 8
    for (int g = 0; g < KG; ++g)
        acc = __builtin_amdgcn_mfma_f32_32x32x16_bf16(a0[g * 64], b0[g * 64], acc, 0, 0, 0);
    int col = lane & 31, rq = (lane >> 5) * 4;

    // epilogue pass 1: v = acc (+bias) + resid; write f32; stash v in acc.
    #pragma unroll
    for (int r = 0; r < 16; ++r) {
        int row = (r & 3) + 8 * (r >> 2) + rq;
        int m = mw + row;
        int n = n0 + col;
        float v = acc[r];
        if (BIAS) v += bias[n];
        v += resid[(size_t)m * DD + n];
        out_f32[(size_t)m * DD + n] = v;
        acc[r] = v;
    }

    // per-wave row sums over this wave's 32 cols (16 slots, 4 stages + xor16).
    {
        float ps[16];
        #pragma unroll
        for (int r = 0; r < 16; ++r) ps[r] = acc[r];
        redstage<1, 16>(ps, lane);
        redstage<2, 8>(ps, lane);
        redstage<4, 4>(ps, lane);
        redstage<8, 2>(ps, lane);
        float sum32 = ps[0] + __shfl_xor(ps[0], 16, 64);
        float qs[16];
        #pragma unroll
        for (int r = 0; r < 16; ++r) qs[r] = acc[r] * acc[r];
        redstage<1, 16>(qs, lane);
        redstage<2, 8>(qs, lane);
        redstage<4, 4>(qs, lane);
        redstage<8, 2>(qs, lane);
        float sq32 = qs[0] + __shfl_xor(qs[0], 16, 64);
        int slot = lane & 15;
        int ROW = wm * 32 + (slot & 3) + 8 * (slot >> 2) + rq;
        if ((lane & 16) == 0)
            *reinterpret_cast<float2*>(&pstat[wn][ROW][0]) = make_float2(sum32, sq32);
    }
    __syncthreads();
    if (threadIdx.x < 64) {
        int R = threadIdx.x;
        float s = 0.0f, sq = 0.0f;
        #pragma unroll
        for (int w = 0; w < 8; ++w) {
            float2 p = *reinterpret_cast<float2*>(&pstat[w][R][0]);
            s += p.x; sq += p.y;
        }
        float mean = s * (1.0f / DD);
        float var = sq * (1.0f / DD) - mean * mean;
        float rstd = rsqrtf(var + 1e-5f);
        *reinterpret_cast<float2*>(&stats[R][0]) = make_float2(mean, rstd);
    }
    __syncthreads();

    // normalize + transpose-pack to frags (pad-33 wave-private tiles).
    float* wlds = &tlds[wave][0];
    float mean_r[16], rstd_r[16];
    #pragma unroll
    for (int r = 0; r < 16; ++r) {
        int row = (r & 3) + 8 * (r >> 2) + rq;
        float2 st = *reinterpret_cast<float2*>(&stats[wm * 32 + row][0]);
        mean_r[r] = st.x; rstd_r[r] = st.y;
    }
    float gj = lng[n0 + col];
    float bj = lnb[n0 + col];
    #pragma unroll
    for (int r = 0; r < 16; ++r) {
        int row = (r & 3) + 8 * (r >> 2) + rq;
        float v = (acc[r] - mean_r[r]) * rstd_r[r] * gj + bj;
        wlds[row * 33 + col] = v;
    }
    #pragma unroll
    for (int it = 0; it < 2; ++it) {
        int task = lane + it * 64;
        int row = task >> 2, cc = task & 3;
        int m = mw + row;
        int k = n0 + cc * 8;
        float* p = &wlds[row * 33 + cc * 8];
        unsigned short us[8];
        #pragma unroll
        for (int e = 0; e < 8; ++e) us[e] = f2bf(p[e]);
        int chunk = ((m >> 5) * (DD >> 4) + (k >> 4)) * 64 + ((k >> 3) & 1) * 32 + (m & 31);
        *reinterpret_cast<uint4*>(out_frag + (size_t)chunk * 8) = *reinterpret_cast<uint4*>(us);
    }
}

// One wave per point. lane = h*16+s; dims d0 = h*64+s*4.
// Distributed scores; pe handled algebraically. kv rows: 512 B fp8.
// R12: score reduction via butterfly reduce-scatter (15 shfl vs 64).
__global__ __launch_bounds__(256) void attn_kernel(
        const unsigned short* __restrict__ q, const unsigned char* __restrict__ kv,
        const float* __restrict__ coord, const float* __restrict__ ctx_coord,
        const int* __restrict__ knn,
        const float* __restrict__ pe_w, const float* __restrict__ pe_b,
        unsigned short* __restrict__ out_frag) {
    int wave = threadIdx.x >> 6, lane = threadIdx.x & 63;
    int m = blockIdx.x * 4 + wave;
    int s = lane & 15;
    int d0 = (lane >> 4) * 64 + s * 4;

    ushort4 qv4 = *reinterpret_cast<const ushort4*>(q + (size_t)m * DD + d0);
    float qx = bf2f(qv4.x), qy = bf2f(qv4.y), qz = bf2f(qv4.z), qw = bf2f(qv4.w);
    float4 pw0 = *reinterpret_cast<const float4*>(pe_w + d0);
    float4 pw1 = *reinterpret_cast<const float4*>(pe_w + DD + d0);
    float4 pw2 = *reinterpret_cast<const float4*>(pe_w + 2 * DD + d0);
    float4 pbv = *reinterpret_cast<const float4*>(pe_b + d0);

    float cx = coord[m * 3], cy = coord[m * 3 + 1], cz = coord[m * 3 + 2];
    int myidx = knn[(size_t)m * KK + s];
    int icm = myidx < 0 ? 0 : myidx;
    float rx = cx - ctx_coord[icm * 3];
    float ry = cy - ctx_coord[icm * 3 + 1];
    float rz = cz - ctx_coord[icm * 3 + 2];

    float t0 = qx * pw0.x + qy * pw0.y + qz * pw0.z + qw * pw0.w;
    float t1 = qx * pw1.x + qy * pw1.y + qz * pw1.z + qw * pw1.w;
    float t2 = qx * pw2.x + qy * pw2.y + qz * pw2.z + qw * pw2.w;
    float t3 = qx * pbv.x + qy * pbv.y + qz * pbv.z + qw * pbv.w;
    #pragma unroll
    for (int o = 1; o < 16; o <<= 1) {
        t0 += __shfl_xor(t0, o, 64);
        t1 += __shfl_xor(t1, o, 64);
        t2 += __shfl_xor(t2, o, 64);
        t3 += __shfl_xor(t3, o, 64);
    }

    // per-lane partials for all 16 scores, then one butterfly reduce-scatter
    float P[KK];
    unsigned vpk[KK];
    #pragma unroll
    for (int j = 0; j < KK; ++j) {
        int ij = __shfl(myidx, j, 64);
        int ic = ij < 0 ? 0 : ij;
        uint2 kvv = *reinterpret_cast<const uint2*>(kv + (size_t)ic * 512 + (d0 >> 2) * 8);
        vpk[j] = kvv.y;
        f32x2 k01 = __builtin_amdgcn_cvt_pk_f32_fp8(kvv.x, false);
        f32x2 k23 = __builtin_amdgcn_cvt_pk_f32_fp8(kvv.x, true);
        P[j] = qx * k01.x + qy * k01.y + qz * k23.x + qw * k23.y;
    }
    redstage<1, 16>(P, lane);
    redstage<2, 8>(P, lane);
    redstage<4, 4>(P, lane);
    redstage<8, 2>(P, lane);
    float corr = rx * t0 + ry * t1 + rz * t2 + t3;
    float sc_own = (myidx >= 0) ? (P[0] + corr) * 0.125f : -1e9f;

    float mx = sc_own;
    mx = fmaxf(mx, __shfl_xor(mx, 1, 64));
    mx = fmaxf(mx, __shfl_xor(mx, 2, 64));
    mx = fmaxf(mx, __shfl_xor(mx, 4, 64));
    mx = fmaxf(mx, __shfl_xor(mx, 8, 64));
    float e = __expf(sc_own - mx);
    float sum = e;
    sum += __shfl_xor(sum, 1, 64);
    sum += __shfl_xor(sum, 2, 64);
    sum += __shfl_xor(sum, 4, 64);
    sum += __shfl_xor(sum, 8, 64);
    float w_own = e * __frcp_rn(sum);

    float wrx = w_own * rx, wry = w_own * ry, wrz = w_own * rz;
    #pragma unroll
    for (int o = 1; o < 16; o <<= 1) {
        wrx += __shfl_xor(wrx, o, 64);
        wry += __shfl_xor(wry, o, 64);
        wrz += __shfl_xor(wrz, o, 64);
    }

    int gbase = lane & 48;
    float ax = 0.f, ay = 0.f, az = 0.f, aw = 0.f;
    #pragma unroll
    for (int j = 0; j < KK; ++j) {
        float wj = __shfl(w_own, gbase + j, 64);
        f32x2 v01 = __builtin_amdgcn_cvt_pk_f32_fp8(vpk[j], false);
        f32x2 v23 = __builtin_amdgcn_cvt_pk_f32_fp8(vpk[j], true);
        ax += wj * v01.x;
        ay += wj * v01.y;
        az += wj * v23.x;
        aw += wj * v23.y;
    }
    ax += wrx * pw0.x + wry * pw1.x + wrz * pw2.x + pbv.x;
    ay += wrx * pw0.y + wry * pw1.y + wrz * pw2.y + pbv.y;
    az += wrx * pw0.z + wry * pw1.z + wrz * pw2.z + pbv.z;
    aw += wrx * pw0.w + wry * pw1.w + wrz * pw2.w + pbv.w;

    ushort4 o4 = make_ushort4(f2bf(ax), f2bf(ay), f2bf(az), f2bf(aw));
    int chunk = ((m >> 5) * (DD >> 4) + (d0 >> 4)) * 64 + ((d0 >> 3) & 1) * 32 + (m & 31);
    *reinterpret_cast<ushort4*>(out_frag + (size_t)chunk * 8 + (d0 & 7)) = o4;
}

extern "C" void kernel_launch(void* const* d_in, const int* in_sizes, int n_in,
                              void* d_out, int out_size, void* d_ws, size_t ws_size,
                              hipStream_t stream) {
    const float* feat_a = (const float*)d_in[0];
    const float* coord_a = (const float*)d_in[1];
    const float* feat_b = (const float*)d_in[2];
    const float* coord_b = (const float*)d_in[3];
    const float* Wq = (const float*)d_in[4];
    const float* Wk = (const float*)d_in[5];
    const float* Wv = (const float*)d_in[6];
    const float* Wo = (const float*)d_in[7];
    const float* ln1_g = (const float*)d_in[8];
    const float* ln1_b = (const float*)d_in[9];
    const float* pe_w = (const float*)d_in[10];
    const float* pe_b = (const float*)d_in[11];
    const float* W1 = (const float*)d_in[12];
    const float* b1 = (const float*)d_in[13];
    const float* W2 = (const float*)d_in[14];
    const float* b2 = (const float*)d_in[15];
    const float* ln2_g = (const float*)d_in[16];
    const float* ln2_b = (const float*)d_in[17];
    const int* knn_a2a = (const int*)d_in[18];
    const int* knn_a2b = (const int*)d_in[19];

    char* ws = (char*)d_ws;
    unsigned short* wfrag = (unsigned short*)ws;                  // 3 MB (4 MB region)
    float* xmid = (float*)(ws + (4ull << 20));                    // 16 MB
    float* xout0 = (float*)(ws + (20ull << 20));                  // 16 MB
    unsigned short* qbuf = (unsigned short*)(ws + (36ull << 20)); // 8 MB
    unsigned char* kvbuf = (unsigned char*)(ws + (52ull << 20));  // 8 MB (fp8)
    unsigned short* xnf = (unsigned short*)(ws + (68ull << 20));  // 8 MB
    unsigned short* ctxfa = (unsigned short*)(ws + (76ull << 20));// 8 MB
    unsigned short* attnf = (unsigned short*)(ws + (84ull << 20));// 8 MB
    unsigned short* ctxfb = (unsigned short*)(ws + (92ull << 20));// 8 MB -> 100 MB
    unsigned short* geluf = (unsigned short*)(ws + (36ull << 20));// 32 MB, overlays q/kv (dead by FFN)

    const unsigned short* WQF = wfrag;
    const unsigned short* KVF = wfrag + 131072;
    const unsigned short* WOF = wfrag + 393216;
    const unsigned short* W1F = wfrag + 524288;
    const unsigned short* W2F = wfrag + 1048576;

    prep_weights<<<(1572864 + 255) / 256, 256, 0, stream>>>(Wq, Wk, Wv, Wo, W1, W2, wfrag);

    // one launch: xnf = LN1(feat_a); ctxfa = conv(feat_a); ctxfb = conv(feat_b)
    ln3_to_frag<<<dim3(MM / 4, 3), 256, 0, stream>>>(feat_a, ln1_g, ln1_b, feat_b,
                                                     xnf, ctxfa, ctxfb);

    // ---- block 0: self(a) ----
    gemm_qkv<<<dim3(MM / 128, 6), 512, 0, stream>>>(
        (const bf16x8*)xnf, (const bf16x8*)ctxfa,
        (const bf16x8*)WQF, (const bf16x8*)KVF, qbuf, kvbuf);

    attn_kernel<<<MM / 4, 256, 0, stream>>>(qbuf, kvbuf, coord_a, coord_a, knn_a2a,
                                            pe_w, pe_b, attnf);

    // Wo-GEMM + resid + LN2 -> xmid (f32) and xnf (frags)
    gemm_ln<256, false><<<MM / 64, 1024, 0, stream>>>(
        (const bf16x8*)attnf, (const bf16x8*)WOF, xmid, feat_a, nullptr,
        ln2_g, ln2_b, xnf);

    gemm_frag<256, 1024, GOUT_GELU_FRAG, false, true><<<dim3(MM / 128, 8), 256, 0, stream>>>(
        (const bf16x8*)xnf, (const bf16x8*)W1F, geluf, nullptr, b1, 1024);

    // FFN2 + resid + LN1(blk1) -> xout0 (f32) and xnf (frags for blk1 Q-proj)
    gemm_ln<1024, true><<<MM / 64, 1024, 0, stream>>>(
        (const bf16x8*)geluf, (const bf16x8*)W2F, xout0, xmid, b2,
        ln1_g + DD, ln1_b + DD, xnf);

    // ---- block 1: cross(a,b) ----
    gemm_qkv<<<dim3(MM / 128, 6), 512, 0, stream>>>(
        (const bf16x8*)xnf, (const bf16x8*)ctxfb,
        (const bf16x8*)(WQF + 65536), (const bf16x8*)(KVF + 131072), qbuf, kvbuf);

    attn_kernel<<<MM / 4, 256, 0, stream>>>(qbuf, kvbuf, coord_a, coord_b, knn_a2b,
                                            pe_w + 3 * DD, pe_b + DD, attnf);

    gemm_ln<256, false><<<MM / 64, 1024, 0, stream>>>(
        (const bf16x8*)attnf, (const bf16x8*)(WOF + 65536), xmid, xout0, nullptr,
        ln2_g + DD, ln2_b + DD, xnf);

    gemm_frag<256, 1024, GOUT_GELU_FRAG, false, true><<<dim3(MM / 128, 8), 256, 0, stream>>>(
        (const bf16x8*)xnf, (const bf16x8*)(W1F + 262144), geluf, nullptr,
        b1 + DFF_, 1024);

    // final FFN2: 64x128 tiles, 8 waves, grid (256,2) -> 4 waves/SIMD
    gemm_frag64<1024, 256, true, true><<<dim3(MM / 64, 2), 512, 0, stream>>>(
        (const bf16x8*)geluf, (const bf16x8*)(W2F + 262144), (float*)d_out, xmid,
        b2 + DD);
}

// Round 7
// 309.850 us; speedup vs baseline: 1.0386x; 1.0386x over previous
//
#include <hip/hip_runtime.h>
#include <hip/hip_bf16.h>
#include <stdint.h>

#define MM 16384
#define DD 256
#define HH 4
#define KK 16
#define DFF_ 1024

typedef __attribute__((ext_vector_type(8))) short bf16x8;
typedef __attribute__((ext_vector_type(16))) float f32x16;
typedef __attribute__((ext_vector_type(2))) float f32x2;

__device__ __forceinline__ unsigned short f2bf(float f) {
    unsigned u = __builtin_bit_cast(unsigned, f);
    unsigned r = u + 0x7fffu + ((u >> 16) & 1u);
    return (unsigned short)(r >> 16);
}
__device__ __forceinline__ float bf2f(unsigned short h) {
    unsigned u = ((unsigned)h) << 16;
    return __builtin_bit_cast(float, u);
}

// ---------------------------------------------------------------------------
// Fragment layouts (bf16, 16B chunks of 8 elems):
// A-frag (row m, k):  chunk = ((m>>5)*(KD/16) + (k>>4))*64 + ((k>>3)&1)*32 + (m&31), elem = k&7
// B-frag (col n, k):  same with n.
// v_mfma_f32_32x32x16_bf16 C/D: col=lane&31, row=(reg&3)+8*(reg>>2)+4*(lane>>5)
// kv buffer: fp8 e4m3 rows of 512 B, groups of 8 B = [K4 | V4].
// NOTE (R5): gelu: sigmoid form + pad-33 LDS + no barriers.
// NOTE (R9/R11/R12): ALL LDS-staging variants lose to direct frag loads.
// NOTE (R10): gemm_ln fusion (Wo+LN2, FFN2+LN1') + ln3 merge: 349->335.7us.
// NOTE (R14): GRID STARVATION is the real lever: 335.7->311.8us.
// NOTE (R15): 32-col wave tiles everywhere REGRESSED (+10us): doubling
//   per-element A-traffic outweighs extra waves. 64-col min for B-reuse.
//   BUT rocprof exposed FFN1: 48.5us x2, MfmaUtil 6%, Occ 24% = starved.
// NOTE (R16/this round): revert qkv/gemm_ln/FFN2 to R14 shapes; FFN1 ->
//   gemm_gelu: 64x128 wg (4 waves of 32x64, B-reuse kept), grid (256,8)
//   = 8 wgs/CU (4x residency), epilogue halved per wave.
// ---------------------------------------------------------------------------

// wfrag layout (shorts): WQF@0 (blk stride 65536), KVF@131072 (131072),
//   WOF@393216 (65536), W1F@524288 (262144), W2F@1048576 (262144)
__global__ __launch_bounds__(256) void prep_weights(
        const float* __restrict__ Wq, const float* __restrict__ Wk,
        const float* __restrict__ Wv, const float* __restrict__ Wo,
        const float* __restrict__ W1, const float* __restrict__ W2,
        unsigned short* __restrict__ wf) {
    int t = blockIdx.x * blockDim.x + threadIdx.x;
    const float* src; unsigned short* dst;
    int kd, lg, rem, blk, e, sect;
    if (t < 131072) { sect = 0; rem = t; blk = rem >> 16; e = rem & 65535;
        src = Wq; dst = wf + blk * 65536; kd = 256; lg = 8; }
    else if (t < 262144) { sect = 1; rem = t - 131072; blk = rem >> 16; e = rem & 65535;
        src = Wk; dst = wf + 131072 + blk * 131072; kd = 256; lg = 8; }
    else if (t < 393216) { sect = 2; rem = t - 262144; blk = rem >> 16; e = rem & 65535;
        src = Wv; dst = wf + 131072 + blk * 131072; kd = 256; lg = 8; }
    else if (t < 524288) { sect = 0; rem = t - 393216; blk = rem >> 16; e = rem & 65535;
        src = Wo; dst = wf + 393216 + blk * 65536; kd = 256; lg = 8; }
    else if (t < 1048576) { sect = 0; rem = t - 524288; blk = rem >> 18; e = rem & 262143;
        src = W1; dst = wf + 524288 + blk * 262144; kd = 256; lg = 10; }
    else if (t < 1572864) { sect = 0; rem = t - 1048576; blk = rem >> 18; e = rem & 262143;
        src = W2; dst = wf + 1048576 + blk * 262144; kd = 1024; lg = 8; }
    else return;
    int k = e >> lg;
    int n = e & ((1 << lg) - 1);
    if (sect == 1) n = (n >> 2) * 8 + (n & 3);
    else if (sect == 2) n = (n >> 2) * 8 + 4 + (n & 3);
    float v = src[(size_t)blk * kd * (1 << lg) + e];
    int off = ((n >> 5) * (kd >> 4) + (k >> 4)) * 512 + (((k >> 3) & 1) * 32 + (n & 31)) * 8 + (k & 7);
    dst[off] = f2bf(v);
}

// 3 slices in one launch: y=0: LN(xa,g,b)->outln; y=1: conv(xa)->outca; y=2: conv(xb)->outcb
__global__ __launch_bounds__(256) void ln3_to_frag(
        const float* __restrict__ xa, const float* __restrict__ g,
        const float* __restrict__ b, const float* __restrict__ xb,
        unsigned short* __restrict__ outln, unsigned short* __restrict__ outca,
        unsigned short* __restrict__ outcb) {
    int y = blockIdx.y;
    const float* x = (y == 2) ? xb : xa;
    unsigned short* out = (y == 0) ? outln : (y == 1 ? outca : outcb);
    int apply_ln = (y == 0);
    int wave = threadIdx.x >> 6, lane = threadIdx.x & 63;
    int m = blockIdx.x * 4 + wave;
    const float4 xv = reinterpret_cast<const float4*>(x + (size_t)m * DD)[lane];
    float vals[4] = {xv.x, xv.y, xv.z, xv.w};
    int k0 = lane * 4;
    if (apply_ln) {
        float s = vals[0] + vals[1] + vals[2] + vals[3];
        float sq = vals[0]*vals[0] + vals[1]*vals[1] + vals[2]*vals[2] + vals[3]*vals[3];
        for (int o = 32; o; o >>= 1) { s += __shfl_xor(s, o, 64); sq += __shfl_xor(sq, o, 64); }
        float mean = s * (1.0f / DD);
        float var = sq * (1.0f / DD) - mean * mean;
        float rs = rsqrtf(var + 1e-5f);
        #pragma unroll
        for (int c = 0; c < 4; ++c)
            vals[c] = (vals[c] - mean) * rs * g[k0 + c] + b[k0 + c];
    }
    int chunk = ((m >> 5) * (DD >> 4) + (k0 >> 4)) * 64 + ((k0 >> 3) & 1) * 32 + (m & 31);
    ushort4 o4 = make_ushort4(f2bf(vals[0]), f2bf(vals[1]), f2bf(vals[2]), f2bf(vals[3]));
    *reinterpret_cast<ushort4*>(out + (size_t)chunk * 8 + (k0 & 7)) = o4;
}

template <int KG>
__device__ __forceinline__ void compute_tile(
        const bf16x8* __restrict__ a0, const bf16x8* __restrict__ a1,
        const bf16x8* __restrict__ b0, const bf16x8* __restrict__ b1,
        f32x16 acc[2][2]) {
    #pragma unroll 4
    for (int g = 0; g < KG; ++g) {
        bf16x8 av0 = a0[g * 64];
        bf16x8 av1 = a1[g * 64];
        bf16x8 bv0 = b0[g * 64];
        bf16x8 bv1 = b1[g * 64];
        acc[0][0] = __builtin_amdgcn_mfma_f32_32x32x16_bf16(av0, bv0, acc[0][0], 0, 0, 0);
        acc[0][1] = __builtin_amdgcn_mfma_f32_32x32x16_bf16(av0, bv1, acc[0][1], 0, 0, 0);
        acc[1][0] = __builtin_amdgcn_mfma_f32_32x32x16_bf16(av1, bv0, acc[1][0], 0, 0, 0);
        acc[1][1] = __builtin_amdgcn_mfma_f32_32x32x16_bf16(av1, bv1, acc[1][1], 0, 0, 0);
    }
}

// R16: FFN1 + GELU -> bf16 A-frag. wg = 64x128 (4 waves 2m x 2n of 32x64),
// grid (M/64, DFF/128) = 2048 wgs -> 8 wgs/CU. B-reuse per wave kept at 64
// cols; acc 32 regs; epilogue 32 GELU elems/lane.
template <int KD, int NOUT>
__global__ __launch_bounds__(256) void gemm_gelu(
        const bf16x8* __restrict__ A, const bf16x8* __restrict__ B,
        unsigned short* __restrict__ outp, const float* __restrict__ bias,
        int out_kd) {
    constexpr int KG = KD / 16;
    __shared__ float lds[4 * 1056];
    int wave = threadIdx.x >> 6, lane = threadIdx.x & 63;
    int wm = wave & 1, wn = wave >> 1;
    int mw = blockIdx.x * 64 + wm * 32;
    int nw = blockIdx.y * 128 + wn * 64;
    const bf16x8* a0 = A + ((size_t)(mw >> 5) * KG) * 64 + lane;
    const bf16x8* b0 = B + ((size_t)(nw >> 5) * KG) * 64 + lane;
    const bf16x8* b1 = b0 + (size_t)KG * 64;
    f32x16 acc[2] = {};
    #pragma unroll 4
    for (int g = 0; g < KG; ++g) {
        bf16x8 av = a0[g * 64];
        bf16x8 bv0 = b0[g * 64];
        bf16x8 bv1 = b1[g * 64];
        acc[0] = __builtin_amdgcn_mfma_f32_32x32x16_bf16(av, bv0, acc[0], 0, 0, 0);
        acc[1] = __builtin_amdgcn_mfma_f32_32x32x16_bf16(av, bv1, acc[1], 0, 0, 0);
    }
    int col = lane & 31, rq = (lane >> 5) * 4;
    float* wlds = &lds[wave * 1056];
    for (int j = 0; j < 2; ++j) {
        #pragma unroll
        for (int r = 0; r < 16; ++r) {
            int row = (r & 3) + 8 * (r >> 2) + rq;
            int n = nw + j * 32 + col;
            float v = acc[j][r] + bias[n];
            float arg = v * (1.5957691216f + 0.0713548163f * v * v);
            v = v * __frcp_rn(1.0f + __expf(-arg));
            wlds[row * 33 + col] = v;
        }
        #pragma unroll
        for (int it = 0; it < 2; ++it) {
            int task = lane + it * 64;
            int row = task >> 2, cc = task & 3;
            int m = mw + row;
            int k = nw + j * 32 + cc * 8;
            float* p = &wlds[row * 33 + cc * 8];
            unsigned short us[8];
            #pragma unroll
            for (int e = 0; e < 8; ++e) us[e] = f2bf(p[e]);
            int chunk = ((m >> 5) * (out_kd >> 4) + (k >> 4)) * 64 + ((k >> 3) & 1) * 32 + (m & 31);
            reinterpret_cast<uint4*>(outp)[chunk] = *reinterpret_cast<uint4*>(us);
        }
    }
}

// R14 form: final FFN2. 64x128 wg tile, 4 waves = 2m x 2n of 32x64 each.
template <int KD, int NOUT, bool RESID, bool BIAS>
__global__ __launch_bounds__(256) void gemm_frag64(
        const bf16x8* __restrict__ A, const bf16x8* __restrict__ B,
        float* __restrict__ outp, const float* __restrict__ resid,
        const float* __restrict__ bias) {
    constexpr int KG = KD / 16;
    int wave = threadIdx.x >> 6, lane = threadIdx.x & 63;
    int wm = wave & 1, wn = wave >> 1;
    int mw = blockIdx.x * 64 + wm * 32;
    int nw = blockIdx.y * 128 + wn * 64;
    const bf16x8* a0 = A + ((size_t)(mw >> 5) * KG) * 64 + lane;
    const bf16x8* b0 = B + ((size_t)(nw >> 5) * KG) * 64 + lane;
    const bf16x8* b1 = b0 + (size_t)KG * 64;
    f32x16 acc[2] = {};
    #pragma unroll 4
    for (int g = 0; g < KG; ++g) {
        bf16x8 av = a0[g * 64];
        bf16x8 bv0 = b0[g * 64];
        bf16x8 bv1 = b1[g * 64];
        acc[0] = __builtin_amdgcn_mfma_f32_32x32x16_bf16(av, bv0, acc[0], 0, 0, 0);
        acc[1] = __builtin_amdgcn_mfma_f32_32x32x16_bf16(av, bv1, acc[1], 0, 0, 0);
    }
    int col = lane & 31, rq = (lane >> 5) * 4;
    #pragma unroll
    for (int j = 0; j < 2; ++j) {
        #pragma unroll
        for (int r = 0; r < 16; ++r) {
            int row = (r & 3) + 8 * (r >> 2) + rq;
            int m = mw + row;
            int n = nw + j * 32 + col;
            float v = acc[j][r];
            if (BIAS) v += bias[n];
            if (RESID) v += resid[(size_t)m * NOUT + n];
            outp[(size_t)m * NOUT + n] = v;
        }
    }
}

// R14/R10 form: fused Q + KV projections, 128x128 wg tiles, direct loads.
__global__ __launch_bounds__(256) void gemm_qkv(
        const bf16x8* __restrict__ Aq, const bf16x8* __restrict__ Akv,
        const bf16x8* __restrict__ Bq, const bf16x8* __restrict__ Bkv,
        unsigned short* __restrict__ qout, unsigned char* __restrict__ kvout) {
    constexpr int KG = 16;
    int wave = threadIdx.x >> 6, lane = threadIdx.x & 63;
    int wm = wave & 1, wn = wave >> 1;
    int y = blockIdx.y;
    bool isQ = y < 2;
    const bf16x8* A = isQ ? Aq : Akv;
    const bf16x8* B = isQ ? Bq : Bkv;
    int n0 = (isQ ? y : y - 2) * 128 + wn * 64;
    int m0 = blockIdx.x * 128 + wm * 64;
    const bf16x8* a0 = A + ((size_t)(m0 >> 5) * KG) * 64 + lane;
    const bf16x8* a1 = a0 + (size_t)KG * 64;
    const bf16x8* b0 = B + ((size_t)(n0 >> 5) * KG) * 64 + lane;
    const bf16x8* b1 = b0 + (size_t)KG * 64;
    f32x16 acc[2][2] = {};
    compute_tile<KG>(a0, a1, b0, b1, acc);
    int col = lane & 31, rq = (lane >> 5) * 4;
    #pragma unroll
    for (int i = 0; i < 2; ++i)
    #pragma unroll
    for (int j = 0; j < 2; ++j)
    #pragma unroll
    for (int r = 0; r < 16; ++r) {
        int row = (r & 3) + 8 * (r >> 2) + rq;
        int m = m0 + i * 32 + row;
        int n = n0 + j * 32 + col;
        float v = acc[i][j][r];
        if (isQ) qout[(size_t)m * 256 + n] = f2bf(v);
        else kvout[(size_t)m * 512 + n] =
            (unsigned char)(__builtin_amdgcn_cvt_pk_fp8_f32(v, v, 0, false) & 0xff);
    }
}

// butterfly reduce-scatter stage: N slots -> N/2 slots (xor-butterfly).
template <int O, int N>
__device__ __forceinline__ void redstage(float* a, int lane) {
    int sel = lane & O;
    #pragma unroll
    for (int u = 0; u < N / 2; ++u) {
        float lo = a[2 * u], hi = a[2 * u + 1];
        float keep = sel ? hi : lo;
        float send = sel ? lo : hi;
        a[u] = keep + __shfl_xor(send, O, 64);
    }
}

// R14 form: Fused GEMM(+bias)+resid -> f32 C; LayerNorm rows -> bf16 A-frag.
// wg = 64 rows x 256 cols with 8 waves (512 thr), 2m x 4n of 32x64.
template <int KD, bool BIAS>
__global__ __launch_bounds__(512) void gemm_ln(
        const bf16x8* __restrict__ A, const bf16x8* __restrict__ B,
        float* __restrict__ out_f32, const float* __restrict__ resid,
        const float* __restrict__ bias,
        const float* __restrict__ lng, const float* __restrict__ lnb,
        unsigned short* __restrict__ out_frag) {
    constexpr int KG = KD / 16;
    __shared__ float pstat[4][64][2];   // [wn][block row][sum,sumsq]
    __shared__ float stats[64][2];      // [block row][mean, rstd]
    __shared__ float tlds[8][32 * 33];  // per-wave transpose pads
    int wave = threadIdx.x >> 6, lane = threadIdx.x & 63;
    int wm = wave >> 2, wn = wave & 3;
    int m0 = blockIdx.x * 64;
    int mw = m0 + wm * 32;
    int n0 = wn * 64;
    const bf16x8* a0 = A + ((size_t)(mw >> 5) * KG) * 64 + lane;
    const bf16x8* b0 = B + ((size_t)(n0 >> 5) * KG) * 64 + lane;
    const bf16x8* b1 = b0 + (size_t)KG * 64;
    f32x16 acc[2] = {};
    #pragma unroll 4
    for (int g = 0; g < KG; ++g) {
        bf16x8 av = a0[g * 64];
        bf16x8 bv0 = b0[g * 64];
        bf16x8 bv1 = b1[g * 64];
        acc[0] = __builtin_amdgcn_mfma_f32_32x32x16_bf16(av, bv0, acc[0], 0, 0, 0);
        acc[1] = __builtin_amdgcn_mfma_f32_32x32x16_bf16(av, bv1, acc[1], 0, 0, 0);
    }
    int col = lane & 31, rq = (lane >> 5) * 4;

    // epilogue pass 1: v = acc (+bias) + resid; write f32; stash v in acc.
    #pragma unroll
    for (int j = 0; j < 2; ++j) {
        #pragma unroll
        for (int r = 0; r < 16; ++r) {
            int row = (r & 3) + 8 * (r >> 2) + rq;
            int m = mw + row;
            int n = n0 + j * 32 + col;
            float v = acc[j][r];
            if (BIAS) v += bias[n];
            v += resid[(size_t)m * DD + n];
            out_f32[(size_t)m * DD + n] = v;
            acc[j][r] = v;
        }
    }

    // per-wave row sums over this wave's 64 cols (16 slots, 4 stages + xor16).
    {
        float ps[16];
        #pragma unroll
        for (int r = 0; r < 16; ++r)
            ps[r] = acc[0][r] + acc[1][r];
        redstage<1, 16>(ps, lane);
        redstage<2, 8>(ps, lane);
        redstage<4, 4>(ps, lane);
        redstage<8, 2>(ps, lane);
        float sum64 = ps[0] + __shfl_xor(ps[0], 16, 64);
        float qs[16];
        #pragma unroll
        for (int r = 0; r < 16; ++r) {
            float a = acc[0][r], b = acc[1][r];
            qs[r] = a * a + b * b;
        }
        redstage<1, 16>(qs, lane);
        redstage<2, 8>(qs, lane);
        redstage<4, 4>(qs, lane);
        redstage<8, 2>(qs, lane);
        float sq64 = qs[0] + __shfl_xor(qs[0], 16, 64);
        int slot = lane & 15;
        int ROW = wm * 32 + (slot & 3) + 8 * (slot >> 2) + rq;
        if ((lane & 16) == 0)
            *reinterpret_cast<float2*>(&pstat[wn][ROW][0]) = make_float2(sum64, sq64);
    }
    __syncthreads();
    if (threadIdx.x < 64) {
        int R = threadIdx.x;
        float s = 0.0f, sq = 0.0f;
        #pragma unroll
        for (int w = 0; w < 4; ++w) {
            float2 p = *reinterpret_cast<float2*>(&pstat[w][R][0]);
            s += p.x; sq += p.y;
        }
        float mean = s * (1.0f / DD);
        float var = sq * (1.0f / DD) - mean * mean;
        float rstd = rsqrtf(var + 1e-5f);
        *reinterpret_cast<float2*>(&stats[R][0]) = make_float2(mean, rstd);
    }
    __syncthreads();

    // normalize + transpose-pack to frags (pad-33 wave-private tiles).
    float* wlds = &tlds[wave][0];
    float mean_r[16], rstd_r[16];
    #pragma unroll
    for (int r = 0; r < 16; ++r) {
        int row = (r & 3) + 8 * (r >> 2) + rq;
        float2 st = *reinterpret_cast<float2*>(&stats[wm * 32 + row][0]);
        mean_r[r] = st.x; rstd_r[r] = st.y;
    }
    for (int j = 0; j < 2; ++j) {
        float gj = lng[n0 + j * 32 + col];
        float bj = lnb[n0 + j * 32 + col];
        #pragma unroll
        for (int r = 0; r < 16; ++r) {
            int row = (r & 3) + 8 * (r >> 2) + rq;
            float v = (acc[j][r] - mean_r[r]) * rstd_r[r] * gj + bj;
            wlds[row * 33 + col] = v;
        }
        #pragma unroll
        for (int it = 0; it < 2; ++it) {
            int task = lane + it * 64;
            int row = task >> 2, cc = task & 3;
            int m = mw + row;
            int k = n0 + j * 32 + cc * 8;
            float* p = &wlds[row * 33 + cc * 8];
            unsigned short us[8];
            #pragma unroll
            for (int e = 0; e < 8; ++e) us[e] = f2bf(p[e]);
            int chunk = ((m >> 5) * (DD >> 4) + (k >> 4)) * 64 + ((k >> 3) & 1) * 32 + (m & 31);
            *reinterpret_cast<uint4*>(out_frag + (size_t)chunk * 8) = *reinterpret_cast<uint4*>(us);
        }
    }
}

// One wave per point. lane = h*16+s; dims d0 = h*64+s*4.
// Distributed scores; pe handled algebraically. kv rows: 512 B fp8.
// R12: score reduction via butterfly reduce-scatter (15 shfl vs 64).
__global__ __launch_bounds__(256) void attn_kernel(
        const unsigned short* __restrict__ q, const unsigned char* __restrict__ kv,
        const float* __restrict__ coord, const float* __restrict__ ctx_coord,
        const int* __restrict__ knn,
        const float* __restrict__ pe_w, const float* __restrict__ pe_b,
        unsigned short* __restrict__ out_frag) {
    int wave = threadIdx.x >> 6, lane = threadIdx.x & 63;
    int m = blockIdx.x * 4 + wave;
    int s = lane & 15;
    int d0 = (lane >> 4) * 64 + s * 4;

    ushort4 qv4 = *reinterpret_cast<const ushort4*>(q + (size_t)m * DD + d0);
    float qx = bf2f(qv4.x), qy = bf2f(qv4.y), qz = bf2f(qv4.z), qw = bf2f(qv4.w);
    float4 pw0 = *reinterpret_cast<const float4*>(pe_w + d0);
    float4 pw1 = *reinterpret_cast<const float4*>(pe_w + DD + d0);
    float4 pw2 = *reinterpret_cast<const float4*>(pe_w + 2 * DD + d0);
    float4 pbv = *reinterpret_cast<const float4*>(pe_b + d0);

    float cx = coord[m * 3], cy = coord[m * 3 + 1], cz = coord[m * 3 + 2];
    int myidx = knn[(size_t)m * KK + s];
    int icm = myidx < 0 ? 0 : myidx;
    float rx = cx - ctx_coord[icm * 3];
    float ry = cy - ctx_coord[icm * 3 + 1];
    float rz = cz - ctx_coord[icm * 3 + 2];

    float t0 = qx * pw0.x + qy * pw0.y + qz * pw0.z + qw * pw0.w;
    float t1 = qx * pw1.x + qy * pw1.y + qz * pw1.z + qw * pw1.w;
    float t2 = qx * pw2.x + qy * pw2.y + qz * pw2.z + qw * pw2.w;
    float t3 = qx * pbv.x + qy * pbv.y + qz * pbv.z + qw * pbv.w;
    #pragma unroll
    for (int o = 1; o < 16; o <<= 1) {
        t0 += __shfl_xor(t0, o, 64);
        t1 += __shfl_xor(t1, o, 64);
        t2 += __shfl_xor(t2, o, 64);
        t3 += __shfl_xor(t3, o, 64);
    }

    // per-lane partials for all 16 scores, then one butterfly reduce-scatter
    float P[KK];
    unsigned vpk[KK];
    #pragma unroll
    for (int j = 0; j < KK; ++j) {
        int ij = __shfl(myidx, j, 64);
        int ic = ij < 0 ? 0 : ij;
        uint2 kvv = *reinterpret_cast<const uint2*>(kv + (size_t)ic * 512 + (d0 >> 2) * 8);
        vpk[j] = kvv.y;
        f32x2 k01 = __builtin_amdgcn_cvt_pk_f32_fp8(kvv.x, false);
        f32x2 k23 = __builtin_amdgcn_cvt_pk_f32_fp8(kvv.x, true);
        P[j] = qx * k01.x + qy * k01.y + qz * k23.x + qw * k23.y;
    }
    redstage<1, 16>(P, lane);
    redstage<2, 8>(P, lane);
    redstage<4, 4>(P, lane);
    redstage<8, 2>(P, lane);
    float corr = rx * t0 + ry * t1 + rz * t2 + t3;
    float sc_own = (myidx >= 0) ? (P[0] + corr) * 0.125f : -1e9f;

    float mx = sc_own;
    mx = fmaxf(mx, __shfl_xor(mx, 1, 64));
    mx = fmaxf(mx, __shfl_xor(mx, 2, 64));
    mx = fmaxf(mx, __shfl_xor(mx, 4, 64));
    mx = fmaxf(mx, __shfl_xor(mx, 8, 64));
    float e = __expf(sc_own - mx);
    float sum = e;
    sum += __shfl_xor(sum, 1, 64);
    sum += __shfl_xor(sum, 2, 64);
    sum += __shfl_xor(sum, 4, 64);
    sum += __shfl_xor(sum, 8, 64);
    float w_own = e * __frcp_rn(sum);

    float wrx = w_own * rx, wry = w_own * ry, wrz = w_own * rz;
    #pragma unroll
    for (int o = 1; o < 16; o <<= 1) {
        wrx += __shfl_xor(wrx, o, 64);
        wry += __shfl_xor(wry, o, 64);
        wrz += __shfl_xor(wrz, o, 64);
    }

    int gbase = lane & 48;
    float ax = 0.f, ay = 0.f, az = 0.f, aw = 0.f;
    #pragma unroll
    for (int j = 0; j < KK; ++j) {
        float wj = __shfl(w_own, gbase + j, 64);
        f32x2 v01 = __builtin_amdgcn_cvt_pk_f32_fp8(vpk[j], false);
        f32x2 v23 = __builtin_amdgcn_cvt_pk_f32_fp8(vpk[j], true);
        ax += wj * v01.x;
        ay += wj * v01.y;
        az += wj * v23.x;
        aw += wj * v23.y;
    }
    ax += wrx * pw0.x + wry * pw1.x + wrz * pw2.x + pbv.x;
    ay += wrx * pw0.y + wry * pw1.y + wrz * pw2.y + pbv.y;
    az += wrx * pw0.z + wry * pw1.z + wrz * pw2.z + pbv.z;
    aw += wrx * pw0.w + wry * pw1.w + wrz * pw2.w + pbv.w;

    ushort4 o4 = make_ushort4(f2bf(ax), f2bf(ay), f2bf(az), f2bf(aw));
    int chunk = ((m >> 5) * (DD >> 4) + (d0 >> 4)) * 64 + ((d0 >> 3) & 1) * 32 + (m & 31);
    *reinterpret_cast<ushort4*>(out_frag + (size_t)chunk * 8 + (d0 & 7)) = o4;
}

extern "C" void kernel_launch(void* const* d_in, const int* in_sizes, int n_in,
                              void* d_out, int out_size, void* d_ws, size_t ws_size,
                              hipStream_t stream) {
    const float* feat_a = (const float*)d_in[0];
    const float* coord_a = (const float*)d_in[1];
    const float* feat_b = (const float*)d_in[2];
    const float* coord_b = (const float*)d_in[3];
    const float* Wq = (const float*)d_in[4];
    const float* Wk = (const float*)d_in[5];
    const float* Wv = (const float*)d_in[6];
    const float* Wo = (const float*)d_in[7];
    const float* ln1_g = (const float*)d_in[8];
    const float* ln1_b = (const float*)d_in[9];
    const float* pe_w = (const float*)d_in[10];
    const float* pe_b = (const float*)d_in[11];
    const float* W1 = (const float*)d_in[12];
    const float* b1 = (const float*)d_in[13];
    const float* W2 = (const float*)d_in[14];
    const float* b2 = (const float*)d_in[15];
    const float* ln2_g = (const float*)d_in[16];
    const float* ln2_b = (const float*)d_in[17];
    const int* knn_a2a = (const int*)d_in[18];
    const int* knn_a2b = (const int*)d_in[19];

    char* ws = (char*)d_ws;
    unsigned short* wfrag = (unsigned short*)ws;                  // 3 MB (4 MB region)
    float* xmid = (float*)(ws + (4ull << 20));                    // 16 MB
    float* xout0 = (float*)(ws + (20ull << 20));                  // 16 MB
    unsigned short* qbuf = (unsigned short*)(ws + (36ull << 20)); // 8 MB
    unsigned char* kvbuf = (unsigned char*)(ws + (52ull << 20));  // 8 MB (fp8)
    unsigned short* xnf = (unsigned short*)(ws + (68ull << 20));  // 8 MB
    unsigned short* ctxfa = (unsigned short*)(ws + (76ull << 20));// 8 MB
    unsigned short* attnf = (unsigned short*)(ws + (84ull << 20));// 8 MB
    unsigned short* ctxfb = (unsigned short*)(ws + (92ull << 20));// 8 MB -> 100 MB
    unsigned short* geluf = (unsigned short*)(ws + (36ull << 20));// 32 MB, overlays q/kv (dead by FFN)

    const unsigned short* WQF = wfrag;
    const unsigned short* KVF = wfrag + 131072;
    const unsigned short* WOF = wfrag + 393216;
    const unsigned short* W1F = wfrag + 524288;
    const unsigned short* W2F = wfrag + 1048576;

    prep_weights<<<(1572864 + 255) / 256, 256, 0, stream>>>(Wq, Wk, Wv, Wo, W1, W2, wfrag);

    // one launch: xnf = LN1(feat_a); ctxfa = conv(feat_a); ctxfb = conv(feat_b)
    ln3_to_frag<<<dim3(MM / 4, 3), 256, 0, stream>>>(feat_a, ln1_g, ln1_b, feat_b,
                                                     xnf, ctxfa, ctxfb);

    // ---- block 0: self(a) ----
    gemm_qkv<<<dim3(MM / 128, 6), 256, 0, stream>>>(
        (const bf16x8*)xnf, (const bf16x8*)ctxfa,
        (const bf16x8*)WQF, (const bf16x8*)KVF, qbuf, kvbuf);

    attn_kernel<<<MM / 4, 256, 0, stream>>>(qbuf, kvbuf, coord_a, coord_a, knn_a2a,
                                            pe_w, pe_b, attnf);

    // Wo-GEMM + resid + LN2 -> xmid (f32) and xnf (frags)
    gemm_ln<256, false><<<MM / 64, 512, 0, stream>>>(
        (const bf16x8*)attnf, (const bf16x8*)WOF, xmid, feat_a, nullptr,
        ln2_g, ln2_b, xnf);

    // FFN1+GELU: 64x128 wg tiles, grid (256,8) = 2048 wgs -> 8 wgs/CU
    gemm_gelu<256, 1024><<<dim3(MM / 64, 8), 256, 0, stream>>>(
        (const bf16x8*)xnf, (const bf16x8*)W1F, geluf, b1, 1024);

    // FFN2 + resid + LN1(blk1) -> xout0 (f32) and xnf (frags for blk1 Q-proj)
    gemm_ln<1024, true><<<MM / 64, 512, 0, stream>>>(
        (const bf16x8*)geluf, (const bf16x8*)W2F, xout0, xmid, b2,
        ln1_g + DD, ln1_b + DD, xnf);

    // ---- block 1: cross(a,b) ----
    gemm_qkv<<<dim3(MM / 128, 6), 256, 0, stream>>>(
        (const bf16x8*)xnf, (const bf16x8*)ctxfb,
        (const bf16x8*)(WQF + 65536), (const bf16x8*)(KVF + 131072), qbuf, kvbuf);

    attn_kernel<<<MM / 4, 256, 0, stream>>>(qbuf, kvbuf, coord_a, coord_b, knn_a2b,
                                            pe_w + 3 * DD, pe_b + DD, attnf);

    gemm_ln<256, false><<<MM / 64, 512, 0, stream>>>(
        (const bf16x8*)attnf, (const bf16x8*)(WOF + 65536), xmid, xout0, nullptr,
        ln2_g + DD, ln2_b + DD, xnf);

    gemm_gelu<256, 1024><<<dim3(MM / 64, 8), 256, 0, stream>>>(
        (const bf16x8*)xnf, (const bf16x8*)(W1F + 262144), geluf, b1 + DFF_, 1024);

    // final FFN2: 64x128 tiles, grid (256,2) = 512 wgs (R14 form)
    gemm_frag64<1024, 256, true, true><<<dim3(MM / 64, 2), 256, 0, stream>>>(
        (const bf16x8*)geluf, (const bf16x8*)(W2F + 262144), (float*)d_out, xmid,
        b2 + DD);
}

// Round 8
// 309.428 us; speedup vs baseline: 1.0400x; 1.0014x over previous
//
#include <hip/hip_runtime.h>
#include <hip/hip_bf16.h>
#include <stdint.h>

#define MM 16384
#define DD 256
#define HH 4
#define KK 16
#define DFF_ 1024

typedef __attribute__((ext_vector_type(8))) short bf16x8;
typedef __attribute__((ext_vector_type(16))) float f32x16;
typedef __attribute__((ext_vector_type(2))) float f32x2;

__device__ __forceinline__ unsigned short f2bf(float f) {
    unsigned u = __builtin_bit_cast(unsigned, f);
    unsigned r = u + 0x7fffu + ((u >> 16) & 1u);
    return (unsigned short)(r >> 16);
}
__device__ __forceinline__ float bf2f(unsigned short h) {
    unsigned u = ((unsigned)h) << 16;
    return __builtin_bit_cast(float, u);
}

__device__ __forceinline__ void gload_lds16(const void* g, void* l) {
    __builtin_amdgcn_global_load_lds(
        (const __attribute__((address_space(1))) unsigned int*)g,
        (__attribute__((address_space(3))) unsigned int*)l, 16, 0, 0);
}

// ---------------------------------------------------------------------------
// Fragment layouts (bf16, 16B chunks of 8 elems):
// A-frag (row m, k):  chunk = ((m>>5)*(KD/16) + (k>>4))*64 + ((k>>3)&1)*32 + (m&31), elem = k&7
// B-frag (col n, k):  same with n.
// v_mfma_f32_32x32x16_bf16 C/D: col=lane&31, row=(reg&3)+8*(reg>>2)+4*(lane>>5)
// kv buffer: fp8 e4m3 rows of 512 B, groups of 8 B = [K4 | V4].
// NOTE (R5): gelu: sigmoid form + pad-33 LDS + no barriers.
// NOTE (R10): gemm_ln fusion (Wo+LN2, FFN2+LN1') + ln3 merge: 349->335.7us.
// NOTE (R14): GRID STARVATION lever: 335.7->311.8us.
// NOTE (R15): 32-col wave tiles REGRESSED; 64-col min for B-reuse.
// NOTE (R16): FFN1 4x residency: NO effect (~47us) -> occupancy refuted as
//   FFN1 limiter. Model: latency-bound, loads-in-flight capped ~12/wave by
//   VGPR budget; 390MB L2 traffic x 300cyc / (12x16B x waves) ~= 40us ~= obs.
// NOTE (R9/R11/R12): staging failed with stage->vmcnt(0)->barrier->compute
//   (ZERO overlap, the documented anti-pattern).
// NOTE (R17/this round): FFN1 -> 2-phase pipelined staging: global_load_lds
//   (in-flight costs no VGPRs), double-buffered BK=64 chunks, loads for c+2
//   issued DURING compute of c, counted vmcnt(8) (never 0 mid-loop), RAW
//   s_barrier (no __syncthreads vmcnt(0) drain). FFN1 only, for isolation.
// ---------------------------------------------------------------------------

// wfrag layout (shorts): WQF@0 (blk stride 65536), KVF@131072 (131072),
//   WOF@393216 (65536), W1F@524288 (262144), W2F@1048576 (262144)
__global__ __launch_bounds__(256) void prep_weights(
        const float* __restrict__ Wq, const float* __restrict__ Wk,
        const float* __restrict__ Wv, const float* __restrict__ Wo,
        const float* __restrict__ W1, const float* __restrict__ W2,
        unsigned short* __restrict__ wf) {
    int t = blockIdx.x * blockDim.x + threadIdx.x;
    const float* src; unsigned short* dst;
    int kd, lg, rem, blk, e, sect;
    if (t < 131072) { sect = 0; rem = t; blk = rem >> 16; e = rem & 65535;
        src = Wq; dst = wf + blk * 65536; kd = 256; lg = 8; }
    else if (t < 262144) { sect = 1; rem = t - 131072; blk = rem >> 16; e = rem & 65535;
        src = Wk; dst = wf + 131072 + blk * 131072; kd = 256; lg = 8; }
    else if (t < 393216) { sect = 2; rem = t - 262144; blk = rem >> 16; e = rem & 65535;
        src = Wv; dst = wf + 131072 + blk * 131072; kd = 256; lg = 8; }
    else if (t < 524288) { sect = 0; rem = t - 393216; blk = rem >> 16; e = rem & 65535;
        src = Wo; dst = wf + 393216 + blk * 65536; kd = 256; lg = 8; }
    else if (t < 1048576) { sect = 0; rem = t - 524288; blk = rem >> 18; e = rem & 262143;
        src = W1; dst = wf + 524288 + blk * 262144; kd = 256; lg = 10; }
    else if (t < 1572864) { sect = 0; rem = t - 1048576; blk = rem >> 18; e = rem & 262143;
        src = W2; dst = wf + 1048576 + blk * 262144; kd = 1024; lg = 8; }
    else return;
    int k = e >> lg;
    int n = e & ((1 << lg) - 1);
    if (sect == 1) n = (n >> 2) * 8 + (n & 3);
    else if (sect == 2) n = (n >> 2) * 8 + 4 + (n & 3);
    float v = src[(size_t)blk * kd * (1 << lg) + e];
    int off = ((n >> 5) * (kd >> 4) + (k >> 4)) * 512 + (((k >> 3) & 1) * 32 + (n & 31)) * 8 + (k & 7);
    dst[off] = f2bf(v);
}

// 3 slices in one launch: y=0: LN(xa,g,b)->outln; y=1: conv(xa)->outca; y=2: conv(xb)->outcb
__global__ __launch_bounds__(256) void ln3_to_frag(
        const float* __restrict__ xa, const float* __restrict__ g,
        const float* __restrict__ b, const float* __restrict__ xb,
        unsigned short* __restrict__ outln, unsigned short* __restrict__ outca,
        unsigned short* __restrict__ outcb) {
    int y = blockIdx.y;
    const float* x = (y == 2) ? xb : xa;
    unsigned short* out = (y == 0) ? outln : (y == 1 ? outca : outcb);
    int apply_ln = (y == 0);
    int wave = threadIdx.x >> 6, lane = threadIdx.x & 63;
    int m = blockIdx.x * 4 + wave;
    const float4 xv = reinterpret_cast<const float4*>(x + (size_t)m * DD)[lane];
    float vals[4] = {xv.x, xv.y, xv.z, xv.w};
    int k0 = lane * 4;
    if (apply_ln) {
        float s = vals[0] + vals[1] + vals[2] + vals[3];
        float sq = vals[0]*vals[0] + vals[1]*vals[1] + vals[2]*vals[2] + vals[3]*vals[3];
        for (int o = 32; o; o >>= 1) { s += __shfl_xor(s, o, 64); sq += __shfl_xor(sq, o, 64); }
        float mean = s * (1.0f / DD);
        float var = sq * (1.0f / DD) - mean * mean;
        float rs = rsqrtf(var + 1e-5f);
        #pragma unroll
        for (int c = 0; c < 4; ++c)
            vals[c] = (vals[c] - mean) * rs * g[k0 + c] + b[k0 + c];
    }
    int chunk = ((m >> 5) * (DD >> 4) + (k0 >> 4)) * 64 + ((k0 >> 3) & 1) * 32 + (m & 31);
    ushort4 o4 = make_ushort4(f2bf(vals[0]), f2bf(vals[1]), f2bf(vals[2]), f2bf(vals[3]));
    *reinterpret_cast<ushort4*>(out + (size_t)chunk * 8 + (k0 & 7)) = o4;
}

template <int KG>
__device__ __forceinline__ void compute_tile(
        const bf16x8* __restrict__ a0, const bf16x8* __restrict__ a1,
        const bf16x8* __restrict__ b0, const bf16x8* __restrict__ b1,
        f32x16 acc[2][2]) {
    #pragma unroll 4
    for (int g = 0; g < KG; ++g) {
        bf16x8 av0 = a0[g * 64];
        bf16x8 av1 = a1[g * 64];
        bf16x8 bv0 = b0[g * 64];
        bf16x8 bv1 = b1[g * 64];
        acc[0][0] = __builtin_amdgcn_mfma_f32_32x32x16_bf16(av0, bv0, acc[0][0], 0, 0, 0);
        acc[0][1] = __builtin_amdgcn_mfma_f32_32x32x16_bf16(av0, bv1, acc[0][1], 0, 0, 0);
        acc[1][0] = __builtin_amdgcn_mfma_f32_32x32x16_bf16(av1, bv0, acc[1][0], 0, 0, 0);
        acc[1][1] = __builtin_amdgcn_mfma_f32_32x32x16_bf16(av1, bv1, acc[1][1], 0, 0, 0);
    }
}

// R17: FFN1 + GELU, 2-phase pipelined LDS staging.
// wg = 128x128 (4 waves 2m x 2n of 64x64), BK=64 chunks (CKG=4 k-groups),
// double-buffered 32KB LDS. Loads for chunk c+2 issued during compute of c.
// Counted vmcnt(8); raw s_barrier (no implicit drain).
template <int KD, int NOUT>
__global__ __launch_bounds__(256) void gemm_gelu_pipe(
        const char* __restrict__ A, const char* __restrict__ B,
        unsigned short* __restrict__ outp, const float* __restrict__ bias,
        int out_kd) {
    constexpr int KG = KD / 16;      // 16 k-groups total
    constexpr int CKG = 4;           // k-groups per chunk (BK=64)
    constexpr int NCH = KG / CKG;    // 4 chunks
    __shared__ alignas(16) char smem[2][32768];
    int wave = threadIdx.x >> 6, lane = threadIdx.x & 63;
    int wm = wave & 1, wn = wave >> 1;
    int m0 = blockIdx.x * 128, n0 = blockIdx.y * 128;

    // stage chunk c into buffer buf: 32 segs of 1KB (A:0..15, B:16..31),
    // wave w copies segs with s%4==w (8 gload_lds/wave).
    auto stage = [&](int buf, int c) {
        #pragma unroll
        for (int i = 0; i < 8; ++i) {
            int s = i * 4 + wave;
            const char* gsrc;
            if (s < 16) {
                int g = s >> 2, kk = s & 3;
                gsrc = A + ((((size_t)(m0 >> 5) + g) * KG + (size_t)c * CKG + kk) << 10);
            } else {
                int s2 = s - 16;
                int g = s2 >> 2, kk = s2 & 3;
                gsrc = B + ((((size_t)(n0 >> 5) + g) * KG + (size_t)c * CKG + kk) << 10);
            }
            gload_lds16(gsrc + lane * 16, &smem[buf][s << 10]);
        }
    };

    f32x16 acc[2][2] = {};
    stage(0, 0);
    stage(1, 1);
    #pragma unroll
    for (int c = 0; c < NCH; ++c) {
        if (c < NCH - 1) asm volatile("s_waitcnt vmcnt(8)" ::: "memory");
        else             asm volatile("s_waitcnt vmcnt(0)" ::: "memory");
        __builtin_amdgcn_s_barrier();   // all waves' loads for buf[c&1] landed
        const bf16x8* la0 = (const bf16x8*)&smem[c & 1][0] + (2 * wm * CKG) * 64 + lane;
        const bf16x8* la1 = la0 + CKG * 64;
        const bf16x8* lb0 = (const bf16x8*)&smem[c & 1][16384] + (2 * wn * CKG) * 64 + lane;
        const bf16x8* lb1 = lb0 + CKG * 64;
        #pragma unroll
        for (int g = 0; g < CKG; ++g) {
            bf16x8 av0 = la0[g * 64];
            bf16x8 av1 = la1[g * 64];
            bf16x8 bv0 = lb0[g * 64];
            bf16x8 bv1 = lb1[g * 64];
            acc[0][0] = __builtin_amdgcn_mfma_f32_32x32x16_bf16(av0, bv0, acc[0][0], 0, 0, 0);
            acc[0][1] = __builtin_amdgcn_mfma_f32_32x32x16_bf16(av0, bv1, acc[0][1], 0, 0, 0);
            acc[1][0] = __builtin_amdgcn_mfma_f32_32x32x16_bf16(av1, bv0, acc[1][0], 0, 0, 0);
            acc[1][1] = __builtin_amdgcn_mfma_f32_32x32x16_bf16(av1, bv1, acc[1][1], 0, 0, 0);
        }
        __builtin_amdgcn_s_barrier();   // all waves done reading buf[c&1]
        if (c + 2 < NCH) stage(c & 1, c + 2);
    }

    // epilogue: GELU -> bf16 A-frag; reuse smem[0] as wave-private pad tiles.
    int mw = m0 + wm * 64, nw = n0 + wn * 64;
    int col = lane & 31, rq = (lane >> 5) * 4;
    float* wlds = (float*)&smem[0][0] + wave * 1056;
    for (int i = 0; i < 2; ++i)
    for (int j = 0; j < 2; ++j) {
        #pragma unroll
        for (int r = 0; r < 16; ++r) {
            int row = (r & 3) + 8 * (r >> 2) + rq;
            int n = nw + j * 32 + col;
            float v = acc[i][j][r] + bias[n];
            float arg = v * (1.5957691216f + 0.0713548163f * v * v);
            v = v * __frcp_rn(1.0f + __expf(-arg));
            wlds[row * 33 + col] = v;
        }
        #pragma unroll
        for (int it = 0; it < 2; ++it) {
            int task = lane + it * 64;
            int row = task >> 2, cc = task & 3;
            int m = mw + i * 32 + row;
            int k = nw + j * 32 + cc * 8;
            float* p = &wlds[row * 33 + cc * 8];
            unsigned short us[8];
            #pragma unroll
            for (int e = 0; e < 8; ++e) us[e] = f2bf(p[e]);
            int chunk = ((m >> 5) * (out_kd >> 4) + (k >> 4)) * 64 + ((k >> 3) & 1) * 32 + (m & 31);
            reinterpret_cast<uint4*>(outp)[chunk] = *reinterpret_cast<uint4*>(us);
        }
    }
}

// R14 form: final FFN2. 64x128 wg tile, 4 waves = 2m x 2n of 32x64 each.
template <int KD, int NOUT, bool RESID, bool BIAS>
__global__ __launch_bounds__(256) void gemm_frag64(
        const bf16x8* __restrict__ A, const bf16x8* __restrict__ B,
        float* __restrict__ outp, const float* __restrict__ resid,
        const float* __restrict__ bias) {
    constexpr int KG = KD / 16;
    int wave = threadIdx.x >> 6, lane = threadIdx.x & 63;
    int wm = wave & 1, wn = wave >> 1;
    int mw = blockIdx.x * 64 + wm * 32;
    int nw = blockIdx.y * 128 + wn * 64;
    const bf16x8* a0 = A + ((size_t)(mw >> 5) * KG) * 64 + lane;
    const bf16x8* b0 = B + ((size_t)(nw >> 5) * KG) * 64 + lane;
    const bf16x8* b1 = b0 + (size_t)KG * 64;
    f32x16 acc[2] = {};
    #pragma unroll 4
    for (int g = 0; g < KG; ++g) {
        bf16x8 av = a0[g * 64];
        bf16x8 bv0 = b0[g * 64];
        bf16x8 bv1 = b1[g * 64];
        acc[0] = __builtin_amdgcn_mfma_f32_32x32x16_bf16(av, bv0, acc[0], 0, 0, 0);
        acc[1] = __builtin_amdgcn_mfma_f32_32x32x16_bf16(av, bv1, acc[1], 0, 0, 0);
    }
    int col = lane & 31, rq = (lane >> 5) * 4;
    #pragma unroll
    for (int j = 0; j < 2; ++j) {
        #pragma unroll
        for (int r = 0; r < 16; ++r) {
            int row = (r & 3) + 8 * (r >> 2) + rq;
            int m = mw + row;
            int n = nw + j * 32 + col;
            float v = acc[j][r];
            if (BIAS) v += bias[n];
            if (RESID) v += resid[(size_t)m * NOUT + n];
            outp[(size_t)m * NOUT + n] = v;
        }
    }
}

// R14/R10 form: fused Q + KV projections, 128x128 wg tiles, direct loads.
__global__ __launch_bounds__(256) void gemm_qkv(
        const bf16x8* __restrict__ Aq, const bf16x8* __restrict__ Akv,
        const bf16x8* __restrict__ Bq, const bf16x8* __restrict__ Bkv,
        unsigned short* __restrict__ qout, unsigned char* __restrict__ kvout) {
    constexpr int KG = 16;
    int wave = threadIdx.x >> 6, lane = threadIdx.x & 63;
    int wm = wave & 1, wn = wave >> 1;
    int y = blockIdx.y;
    bool isQ = y < 2;
    const bf16x8* A = isQ ? Aq : Akv;
    const bf16x8* B = isQ ? Bq : Bkv;
    int n0 = (isQ ? y : y - 2) * 128 + wn * 64;
    int m0 = blockIdx.x * 128 + wm * 64;
    const bf16x8* a0 = A + ((size_t)(m0 >> 5) * KG) * 64 + lane;
    const bf16x8* a1 = a0 + (size_t)KG * 64;
    const bf16x8* b0 = B + ((size_t)(n0 >> 5) * KG) * 64 + lane;
    const bf16x8* b1 = b0 + (size_t)KG * 64;
    f32x16 acc[2][2] = {};
    compute_tile<KG>(a0, a1, b0, b1, acc);
    int col = lane & 31, rq = (lane >> 5) * 4;
    #pragma unroll
    for (int i = 0; i < 2; ++i)
    #pragma unroll
    for (int j = 0; j < 2; ++j)
    #pragma unroll
    for (int r = 0; r < 16; ++r) {
        int row = (r & 3) + 8 * (r >> 2) + rq;
        int m = m0 + i * 32 + row;
        int n = n0 + j * 32 + col;
        float v = acc[i][j][r];
        if (isQ) qout[(size_t)m * 256 + n] = f2bf(v);
        else kvout[(size_t)m * 512 + n] =
            (unsigned char)(__builtin_amdgcn_cvt_pk_fp8_f32(v, v, 0, false) & 0xff);
    }
}

// butterfly reduce-scatter stage: N slots -> N/2 slots (xor-butterfly).
template <int O, int N>
__device__ __forceinline__ void redstage(float* a, int lane) {
    int sel = lane & O;
    #pragma unroll
    for (int u = 0; u < N / 2; ++u) {
        float lo = a[2 * u], hi = a[2 * u + 1];
        float keep = sel ? hi : lo;
        float send = sel ? lo : hi;
        a[u] = keep + __shfl_xor(send, O, 64);
    }
}

// R14 form: Fused GEMM(+bias)+resid -> f32 C; LayerNorm rows -> bf16 A-frag.
// wg = 64 rows x 256 cols with 8 waves (512 thr), 2m x 4n of 32x64.
template <int KD, bool BIAS>
__global__ __launch_bounds__(512) void gemm_ln(
        const bf16x8* __restrict__ A, const bf16x8* __restrict__ B,
        float* __restrict__ out_f32, const float* __restrict__ resid,
        const float* __restrict__ bias,
        const float* __restrict__ lng, const float* __restrict__ lnb,
        unsigned short* __restrict__ out_frag) {
    constexpr int KG = KD / 16;
    __shared__ float pstat[4][64][2];   // [wn][block row][sum,sumsq]
    __shared__ float stats[64][2];      // [block row][mean, rstd]
    __shared__ float tlds[8][32 * 33];  // per-wave transpose pads
    int wave = threadIdx.x >> 6, lane = threadIdx.x & 63;
    int wm = wave >> 2, wn = wave & 3;
    int m0 = blockIdx.x * 64;
    int mw = m0 + wm * 32;
    int n0 = wn * 64;
    const bf16x8* a0 = A + ((size_t)(mw >> 5) * KG) * 64 + lane;
    const bf16x8* b0 = B + ((size_t)(n0 >> 5) * KG) * 64 + lane;
    const bf16x8* b1 = b0 + (size_t)KG * 64;
    f32x16 acc[2] = {};
    #pragma unroll 4
    for (int g = 0; g < KG; ++g) {
        bf16x8 av = a0[g * 64];
        bf16x8 bv0 = b0[g * 64];
        bf16x8 bv1 = b1[g * 64];
        acc[0] = __builtin_amdgcn_mfma_f32_32x32x16_bf16(av, bv0, acc[0], 0, 0, 0);
        acc[1] = __builtin_amdgcn_mfma_f32_32x32x16_bf16(av, bv1, acc[1], 0, 0, 0);
    }
    int col = lane & 31, rq = (lane >> 5) * 4;

    // epilogue pass 1: v = acc (+bias) + resid; write f32; stash v in acc.
    #pragma unroll
    for (int j = 0; j < 2; ++j) {
        #pragma unroll
        for (int r = 0; r < 16; ++r) {
            int row = (r & 3) + 8 * (r >> 2) + rq;
            int m = mw + row;
            int n = n0 + j * 32 + col;
            float v = acc[j][r];
            if (BIAS) v += bias[n];
            v += resid[(size_t)m * DD + n];
            out_f32[(size_t)m * DD + n] = v;
            acc[j][r] = v;
        }
    }

    // per-wave row sums over this wave's 64 cols (16 slots, 4 stages + xor16).
    {
        float ps[16];
        #pragma unroll
        for (int r = 0; r < 16; ++r)
            ps[r] = acc[0][r] + acc[1][r];
        redstage<1, 16>(ps, lane);
        redstage<2, 8>(ps, lane);
        redstage<4, 4>(ps, lane);
        redstage<8, 2>(ps, lane);
        float sum64 = ps[0] + __shfl_xor(ps[0], 16, 64);
        float qs[16];
        #pragma unroll
        for (int r = 0; r < 16; ++r) {
            float a = acc[0][r], b = acc[1][r];
            qs[r] = a * a + b * b;
        }
        redstage<1, 16>(qs, lane);
        redstage<2, 8>(qs, lane);
        redstage<4, 4>(qs, lane);
        redstage<8, 2>(qs, lane);
        float sq64 = qs[0] + __shfl_xor(qs[0], 16, 64);
        int slot = lane & 15;
        int ROW = wm * 32 + (slot & 3) + 8 * (slot >> 2) + rq;
        if ((lane & 16) == 0)
            *reinterpret_cast<float2*>(&pstat[wn][ROW][0]) = make_float2(sum64, sq64);
    }
    __syncthreads();
    if (threadIdx.x < 64) {
        int R = threadIdx.x;
        float s = 0.0f, sq = 0.0f;
        #pragma unroll
        for (int w = 0; w < 4; ++w) {
            float2 p = *reinterpret_cast<float2*>(&pstat[w][R][0]);
            s += p.x; sq += p.y;
        }
        float mean = s * (1.0f / DD);
        float var = sq * (1.0f / DD) - mean * mean;
        float rstd = rsqrtf(var + 1e-5f);
        *reinterpret_cast<float2*>(&stats[R][0]) = make_float2(mean, rstd);
    }
    __syncthreads();

    // normalize + transpose-pack to frags (pad-33 wave-private tiles).
    float* wlds = &tlds[wave][0];
    float mean_r[16], rstd_r[16];
    #pragma unroll
    for (int r = 0; r < 16; ++r) {
        int row = (r & 3) + 8 * (r >> 2) + rq;
        float2 st = *reinterpret_cast<float2*>(&stats[wm * 32 + row][0]);
        mean_r[r] = st.x; rstd_r[r] = st.y;
    }
    for (int j = 0; j < 2; ++j) {
        float gj = lng[n0 + j * 32 + col];
        float bj = lnb[n0 + j * 32 + col];
        #pragma unroll
        for (int r = 0; r < 16; ++r) {
            int row = (r & 3) + 8 * (r >> 2) + rq;
            float v = (acc[j][r] - mean_r[r]) * rstd_r[r] * gj + bj;
            wlds[row * 33 + col] = v;
        }
        #pragma unroll
        for (int it = 0; it < 2; ++it) {
            int task = lane + it * 64;
            int row = task >> 2, cc = task & 3;
            int m = mw + row;
            int k = n0 + j * 32 + cc * 8;
            float* p = &wlds[row * 33 + cc * 8];
            unsigned short us[8];
            #pragma unroll
            for (int e = 0; e < 8; ++e) us[e] = f2bf(p[e]);
            int chunk = ((m >> 5) * (DD >> 4) + (k >> 4)) * 64 + ((k >> 3) & 1) * 32 + (m & 31);
            *reinterpret_cast<uint4*>(out_frag + (size_t)chunk * 8) = *reinterpret_cast<uint4*>(us);
        }
    }
}

// One wave per point. lane = h*16+s; dims d0 = h*64+s*4.
// Distributed scores; pe handled algebraically. kv rows: 512 B fp8.
// R12: score reduction via butterfly reduce-scatter (15 shfl vs 64).
__global__ __launch_bounds__(256) void attn_kernel(
        const unsigned short* __restrict__ q, const unsigned char* __restrict__ kv,
        const float* __restrict__ coord, const float* __restrict__ ctx_coord,
        const int* __restrict__ knn,
        const float* __restrict__ pe_w, const float* __restrict__ pe_b,
        unsigned short* __restrict__ out_frag) {
    int wave = threadIdx.x >> 6, lane = threadIdx.x & 63;
    int m = blockIdx.x * 4 + wave;
    int s = lane & 15;
    int d0 = (lane >> 4) * 64 + s * 4;

    ushort4 qv4 = *reinterpret_cast<const ushort4*>(q + (size_t)m * DD + d0);
    float qx = bf2f(qv4.x), qy = bf2f(qv4.y), qz = bf2f(qv4.z), qw = bf2f(qv4.w);
    float4 pw0 = *reinterpret_cast<const float4*>(pe_w + d0);
    float4 pw1 = *reinterpret_cast<const float4*>(pe_w + DD + d0);
    float4 pw2 = *reinterpret_cast<const float4*>(pe_w + 2 * DD + d0);
    float4 pbv = *reinterpret_cast<const float4*>(pe_b + d0);

    float cx = coord[m * 3], cy = coord[m * 3 + 1], cz = coord[m * 3 + 2];
    int myidx = knn[(size_t)m * KK + s];
    int icm = myidx < 0 ? 0 : myidx;
    float rx = cx - ctx_coord[icm * 3];
    float ry = cy - ctx_coord[icm * 3 + 1];
    float rz = cz - ctx_coord[icm * 3 + 2];

    float t0 = qx * pw0.x + qy * pw0.y + qz * pw0.z + qw * pw0.w;
    float t1 = qx * pw1.x + qy * pw1.y + qz * pw1.z + qw * pw1.w;
    float t2 = qx * pw2.x + qy * pw2.y + qz * pw2.z + qw * pw2.w;
    float t3 = qx * pbv.x + qy * pbv.y + qz * pbv.z + qw * pbv.w;
    #pragma unroll
    for (int o = 1; o < 16; o <<= 1) {
        t0 += __shfl_xor(t0, o, 64);
        t1 += __shfl_xor(t1, o, 64);
        t2 += __shfl_xor(t2, o, 64);
        t3 += __shfl_xor(t3, o, 64);
    }

    // per-lane partials for all 16 scores, then one butterfly reduce-scatter
    float P[KK];
    unsigned vpk[KK];
    #pragma unroll
    for (int j = 0; j < KK; ++j) {
        int ij = __shfl(myidx, j, 64);
        int ic = ij < 0 ? 0 : ij;
        uint2 kvv = *reinterpret_cast<const uint2*>(kv + (size_t)ic * 512 + (d0 >> 2) * 8);
        vpk[j] = kvv.y;
        f32x2 k01 = __builtin_amdgcn_cvt_pk_f32_fp8(kvv.x, false);
        f32x2 k23 = __builtin_amdgcn_cvt_pk_f32_fp8(kvv.x, true);
        P[j] = qx * k01.x + qy * k01.y + qz * k23.x + qw * k23.y;
    }
    redstage<1, 16>(P, lane);
    redstage<2, 8>(P, lane);
    redstage<4, 4>(P, lane);
    redstage<8, 2>(P, lane);
    float corr = rx * t0 + ry * t1 + rz * t2 + t3;
    float sc_own = (myidx >= 0) ? (P[0] + corr) * 0.125f : -1e9f;

    float mx = sc_own;
    mx = fmaxf(mx, __shfl_xor(mx, 1, 64));
    mx = fmaxf(mx, __shfl_xor(mx, 2, 64));
    mx = fmaxf(mx, __shfl_xor(mx, 4, 64));
    mx = fmaxf(mx, __shfl_xor(mx, 8, 64));
    float e = __expf(sc_own - mx);
    float sum = e;
    sum += __shfl_xor(sum, 1, 64);
    sum += __shfl_xor(sum, 2, 64);
    sum += __shfl_xor(sum, 4, 64);
    sum += __shfl_xor(sum, 8, 64);
    float w_own = e * __frcp_rn(sum);

    float wrx = w_own * rx, wry = w_own * ry, wrz = w_own * rz;
    #pragma unroll
    for (int o = 1; o < 16; o <<= 1) {
        wrx += __shfl_xor(wrx, o, 64);
        wry += __shfl_xor(wry, o, 64);
        wrz += __shfl_xor(wrz, o, 64);
    }

    int gbase = lane & 48;
    float ax = 0.f, ay = 0.f, az = 0.f, aw = 0.f;
    #pragma unroll
    for (int j = 0; j < KK; ++j) {
        float wj = __shfl(w_own, gbase + j, 64);
        f32x2 v01 = __builtin_amdgcn_cvt_pk_f32_fp8(vpk[j], false);
        f32x2 v23 = __builtin_amdgcn_cvt_pk_f32_fp8(vpk[j], true);
        ax += wj * v01.x;
        ay += wj * v01.y;
        az += wj * v23.x;
        aw += wj * v23.y;
    }
    ax += wrx * pw0.x + wry * pw1.x + wrz * pw2.x + pbv.x;
    ay += wrx * pw0.y + wry * pw1.y + wrz * pw2.y + pbv.y;
    az += wrx * pw0.z + wry * pw1.z + wrz * pw2.z + pbv.z;
    aw += wrx * pw0.w + wry * pw1.w + wrz * pw2.w + pbv.w;

    ushort4 o4 = make_ushort4(f2bf(ax), f2bf(ay), f2bf(az), f2bf(aw));
    int chunk = ((m >> 5) * (DD >> 4) + (d0 >> 4)) * 64 + ((d0 >> 3) & 1) * 32 + (m & 31);
    *reinterpret_cast<ushort4*>(out_frag + (size_t)chunk * 8 + (d0 & 7)) = o4;
}

extern "C" void kernel_launch(void* const* d_in, const int* in_sizes, int n_in,
                              void* d_out, int out_size, void* d_ws, size_t ws_size,
                              hipStream_t stream) {
    const float* feat_a = (const float*)d_in[0];
    const float* coord_a = (const float*)d_in[1];
    const float* feat_b = (const float*)d_in[2];
    const float* coord_b = (const float*)d_in[3];
    const float* Wq = (const float*)d_in[4];
    const float* Wk = (const float*)d_in[5];
    const float* Wv = (const float*)d_in[6];
    const float* Wo = (const float*)d_in[7];
    const float* ln1_g = (const float*)d_in[8];
    const float* ln1_b = (const float*)d_in[9];
    const float* pe_w = (const float*)d_in[10];
    const float* pe_b = (const float*)d_in[11];
    const float* W1 = (const float*)d_in[12];
    const float* b1 = (const float*)d_in[13];
    const float* W2 = (const float*)d_in[14];
    const float* b2 = (const float*)d_in[15];
    const float* ln2_g = (const float*)d_in[16];
    const float* ln2_b = (const float*)d_in[17];
    const int* knn_a2a = (const int*)d_in[18];
    const int* knn_a2b = (const int*)d_in[19];

    char* ws = (char*)d_ws;
    unsigned short* wfrag = (unsigned short*)ws;                  // 3 MB (4 MB region)
    float* xmid = (float*)(ws + (4ull << 20));                    // 16 MB
    float* xout0 = (float*)(ws + (20ull << 20));                  // 16 MB
    unsigned short* qbuf = (unsigned short*)(ws + (36ull << 20)); // 8 MB
    unsigned char* kvbuf = (unsigned char*)(ws + (52ull << 20));  // 8 MB (fp8)
    unsigned short* xnf = (unsigned short*)(ws + (68ull << 20));  // 8 MB
    unsigned short* ctxfa = (unsigned short*)(ws + (76ull << 20));// 8 MB
    unsigned short* attnf = (unsigned short*)(ws + (84ull << 20));// 8 MB
    unsigned short* ctxfb = (unsigned short*)(ws + (92ull << 20));// 8 MB -> 100 MB
    unsigned short* geluf = (unsigned short*)(ws + (36ull << 20));// 32 MB, overlays q/kv (dead by FFN)

    const unsigned short* WQF = wfrag;
    const unsigned short* KVF = wfrag + 131072;
    const unsigned short* WOF = wfrag + 393216;
    const unsigned short* W1F = wfrag + 524288;
    const unsigned short* W2F = wfrag + 1048576;

    prep_weights<<<(1572864 + 255) / 256, 256, 0, stream>>>(Wq, Wk, Wv, Wo, W1, W2, wfrag);

    // one launch: xnf = LN1(feat_a); ctxfa = conv(feat_a); ctxfb = conv(feat_b)
    ln3_to_frag<<<dim3(MM / 4, 3), 256, 0, stream>>>(feat_a, ln1_g, ln1_b, feat_b,
                                                     xnf, ctxfa, ctxfb);

    // ---- block 0: self(a) ----
    gemm_qkv<<<dim3(MM / 128, 6), 256, 0, stream>>>(
        (const bf16x8*)xnf, (const bf16x8*)ctxfa,
        (const bf16x8*)WQF, (const bf16x8*)KVF, qbuf, kvbuf);

    attn_kernel<<<MM / 4, 256, 0, stream>>>(qbuf, kvbuf, coord_a, coord_a, knn_a2a,
                                            pe_w, pe_b, attnf);

    // Wo-GEMM + resid + LN2 -> xmid (f32) and xnf (frags)
    gemm_ln<256, false><<<MM / 64, 512, 0, stream>>>(
        (const bf16x8*)attnf, (const bf16x8*)WOF, xmid, feat_a, nullptr,
        ln2_g, ln2_b, xnf);

    // FFN1+GELU: 2-phase pipelined staging, 128x128 tiles, grid (128,8)
    gemm_gelu_pipe<256, 1024><<<dim3(MM / 128, 8), 256, 0, stream>>>(
        (const char*)xnf, (const char*)W1F, geluf, b1, 1024);

    // FFN2 + resid + LN1(blk1) -> xout0 (f32) and xnf (frags for blk1 Q-proj)
    gemm_ln<1024, true><<<MM / 64, 512, 0, stream>>>(
        (const bf16x8*)geluf, (const bf16x8*)W2F, xout0, xmid, b2,
        ln1_g + DD, ln1_b + DD, xnf);

    // ---- block 1: cross(a,b) ----
    gemm_qkv<<<dim3(MM / 128, 6), 256, 0, stream>>>(
        (const bf16x8*)xnf, (const bf16x8*)ctxfb,
        (const bf16x8*)(WQF + 65536), (const bf16x8*)(KVF + 131072), qbuf, kvbuf);

    attn_kernel<<<MM / 4, 256, 0, stream>>>(qbuf, kvbuf, coord_a, coord_b, knn_a2b,
                                            pe_w + 3 * DD, pe_b + DD, attnf);

    gemm_ln<256, false><<<MM / 64, 512, 0, stream>>>(
        (const bf16x8*)attnf, (const bf16x8*)(WOF + 65536), xmid, xout0, nullptr,
        ln2_g + DD, ln2_b + DD, xnf);

    gemm_gelu_pipe<256, 1024><<<dim3(MM / 128, 8), 256, 0, stream>>>(
        (const char*)xnf, (const char*)(W1F + 262144), geluf, b1 + DFF_, 1024);

    // final FFN2: 64x128 tiles, grid (256,2) = 512 wgs (R14 form)
    gemm_frag64<1024, 256, true, true><<<dim3(MM / 64, 2), 256, 0, stream>>>(
        (const bf16x8*)geluf, (const bf16x8*)(W2F + 262144), (float*)d_out, xmid,
        b2 + DD);
}